// Round 6
// baseline (1268.454 us; speedup 1.0000x reference)
//
#include <hip/hip_runtime.h>
#include <hip/hip_bf16.h>
#include <hip/hip_fp16.h>

#define NN 50000
#define NE 400000
#define NBLK 196  // ceil(NN/256)
#define AGG_CHUNK 8

typedef unsigned short u16;
typedef unsigned int u32;
typedef __attribute__((ext_vector_type(8))) short short8;
typedef __attribute__((ext_vector_type(4))) float f32x4;
typedef __attribute__((ext_vector_type(4))) unsigned short u16x4;
typedef __attribute__((ext_vector_type(2))) _Float16 h2;

typedef __attribute__((address_space(1))) const void as1_void;
typedef __attribute__((address_space(3))) void as3_void;

static __device__ __forceinline__ float bf2f(u16 u) {
    return __uint_as_float(((u32)u) << 16);
}
static __device__ __forceinline__ u16 f2bf(float f) {
    u32 x = __float_as_uint(f);
    x += 0x7fffu + ((x >> 16) & 1u);
    return (u16)(x >> 16);
}
static __device__ __forceinline__ u32 packh2(float a, float b) {
    return ((u32)__half_as_ushort(__float2half(b)) << 16) |
           (u32)__half_as_ushort(__float2half(a));
}
static __device__ __forceinline__ float fdot2u(u32 a, u32 b, float c) {
    return __builtin_amdgcn_fdot2(__builtin_bit_cast(h2, a),
                                  __builtin_bit_cast(h2, b), c, false);
}

static __device__ __forceinline__ void gload_lds16(const u16* g, u16* l) {
    __builtin_amdgcn_global_load_lds((as1_void*)g, (as3_void*)l, 16, 0, 0);
}

// ---------------------------------------------------------------------------
// bf16 GEMM: C[M,N] = A[M,K] @ Bt[N,K]^T, epilogue (+bias)(+aux)(relu), bf16 out.
// m97 structure: 128x128 tile, BK=32, 4 waves, 4x4 16x16x32 frags.
// gridDim.y*128 must equal N exactly; M guarded (loads clamped, stores masked).
// ---------------------------------------------------------------------------
__global__ __launch_bounds__(256) void gemm_bt(
    const u16* __restrict__ A, int lda,
    const u16* __restrict__ Bt,
    u16* __restrict__ C, int ldc,
    int M, int K,
    const float* __restrict__ bias,
    const u16* __restrict__ aux, int ld_aux,
    int relu)
{
    __shared__ u16 As[128 * 32];
    __shared__ u16 Bs[128 * 32];

    const int t = threadIdx.x;
    const int w = t >> 6;
    const int lane = t & 63;
    const int quad = lane >> 4;
    const int l15 = lane & 15;
    const int tile_m = blockIdx.x * 128;
    const int tile_n = blockIdx.y * 128;
    const int wm = (w >> 1) * 64;
    const int wn = (w & 1) * 64;

    f32x4 acc[4][4];
#pragma unroll
    for (int r = 0; r < 4; ++r)
#pragma unroll
        for (int c = 0; c < 4; ++c)
            acc[r][c] = (f32x4){0.f, 0.f, 0.f, 0.f};

    int ar0 = tile_m + (t >> 2);      if (ar0 > M - 1) ar0 = M - 1;
    int ar1 = tile_m + 64 + (t >> 2); if (ar1 > M - 1) ar1 = M - 1;
    const int br0 = tile_n + (t >> 2);
    const int br1 = tile_n + 64 + (t >> 2);
    const int koff = (t & 3) * 8;

    u16* lAs0 = As + w * 512;
    u16* lAs1 = As + 2048 + w * 512;
    u16* lBs0 = Bs + w * 512;
    u16* lBs1 = Bs + 2048 + w * 512;

    const u16* Arow0 = A + (size_t)ar0 * lda + koff;
    const u16* Arow1 = A + (size_t)ar1 * lda + koff;
    const u16* Brow0 = Bt + (size_t)br0 * K + koff;
    const u16* Brow1 = Bt + (size_t)br1 * K + koff;

    for (int k0 = 0; k0 < K; k0 += 32) {
        gload_lds16(Arow0 + k0, lAs0);
        gload_lds16(Arow1 + k0, lAs1);
        gload_lds16(Brow0 + k0, lBs0);
        gload_lds16(Brow1 + k0, lBs1);
        __syncthreads();

        short8 af[4], bfr[4];
#pragma unroll
        for (int r = 0; r < 4; ++r)
            af[r] = *(const short8*)&As[(wm + r * 16 + l15) * 32 + quad * 8];
#pragma unroll
        for (int c = 0; c < 4; ++c)
            bfr[c] = *(const short8*)&Bs[(wn + c * 16 + l15) * 32 + quad * 8];
#pragma unroll
        for (int r = 0; r < 4; ++r)
#pragma unroll
            for (int c = 0; c < 4; ++c)
                acc[r][c] = __builtin_amdgcn_mfma_f32_16x16x32_bf16(af[r], bfr[c], acc[r][c], 0, 0, 0);
        __syncthreads();
    }

#pragma unroll
    for (int r = 0; r < 4; ++r) {
#pragma unroll
        for (int c = 0; c < 4; ++c) {
            const int coln = tile_n + wn + c * 16 + l15;
            const float bv = bias ? bias[coln] : 0.0f;
#pragma unroll
            for (int i = 0; i < 4; ++i) {
                const int row = tile_m + wm + r * 16 + quad * 4 + i;
                if (row < M) {
                    float v = acc[r][c][i] + bv;
                    if (aux) v += bf2f(aux[(size_t)row * ld_aux + coln]);
                    if (relu) v = fmaxf(v, 0.f);
                    C[(size_t)row * ldc + coln] = f2bf(v);
                }
            }
        }
    }
}

// ---------------------------------------------------------------------------
// Fused edge message + mean aggregation; Q = eattr@We via readlane + v_dot2.
// PERSISTENT + dynamic contiguous chunks: each wave grabs AGG_CHUNK consecutive
// nodes from a global cursor; edge stream stays sequential within a chunk.
// ---------------------------------------------------------------------------
__global__ __launch_bounds__(256) void edge_agg_fused(
    const u16* __restrict__ P,
    const u32* __restrict__ eattr_p32,
    const u32* __restrict__ WePk,
    const int* __restrict__ row_start,
    const int* __restrict__ src_perm,
    const float* __restrict__ inv_deg,
    const float* __restrict__ eb,
    u16* __restrict__ agg,
    int* __restrict__ ctr)
{
    const int lane = threadIdx.x & 63;
    const int l15 = lane & 15;
    const int col = lane * 4;

    // this lane's 4 columns of We, packed f16 pairs: 16 kpairs x uint4 (loaded once)
    uint4 wpk[16];
#pragma unroll
    for (int kp = 0; kp < 16; ++kp)
        wpk[kp] = *(const uint4*)(WePk + kp * 256 + col);

    // edge bias for this lane's 4 columns (loaded once)
    const float4 ebv = *(const float4*)(eb + col);

    for (;;) {
        int pos0 = 0;
        if (lane == 0) pos0 = atomicAdd(ctr, AGG_CHUNK);
        const int pos = __shfl(pos0, 0, 64);
        if (pos >= NN) break;
        const int pend = (pos + AGG_CHUNK < NN) ? pos + AGG_CHUNK : NN;

        for (int node = pos; node < pend; ++node) {
            u16x4 pdv = *(const u16x4*)(P + (size_t)node * 768 + 256 + col);
            f32x4 pb;
            pb[0] = bf2f(pdv[0]) + ebv.x;
            pb[1] = bf2f(pdv[1]) + ebv.y;
            pb[2] = bf2f(pdv[2]) + ebv.z;
            pb[3] = bf2f(pdv[3]) + ebv.w;

            f32x4 accv = (f32x4){0.f, 0.f, 0.f, 0.f};
            const int s0r = row_start[node], s1r = row_start[node + 1];

            if (s1r > s0r) {
                const int jlast = s1r - 1;
                int j1 = (s0r + 1 < jlast) ? s0r + 1 : jlast;
                int sa = src_perm[s0r];
                int sb = src_perm[j1];
                u16x4 psa = *(const u16x4*)(P + (size_t)sa * 768 + col);
                u16x4 psb = *(const u16x4*)(P + (size_t)sb * 768 + col);
                u32 eva = eattr_p32[(size_t)s0r * 16 + l15];
                u32 evb = eattr_p32[(size_t)j1 * 16 + l15];

                for (int j = s0r; j < s1r; ++j) {
                    int jc = (j + 2 < jlast) ? j + 2 : jlast;
                    int sn = src_perm[jc];
                    u16x4 psn = *(const u16x4*)(P + (size_t)sn * 768 + col);
                    u32 evn = eattr_p32[(size_t)jc * 16 + l15];

                    f32x4 q = pb;
#pragma unroll
                    for (int kp = 0; kp < 16; ++kp) {
                        u32 evk = (u32)__builtin_amdgcn_readlane((int)eva, kp);
                        q[0] = fdot2u(evk, wpk[kp].x, q[0]);
                        q[1] = fdot2u(evk, wpk[kp].y, q[1]);
                        q[2] = fdot2u(evk, wpk[kp].z, q[2]);
                        q[3] = fdot2u(evk, wpk[kp].w, q[3]);
                    }
                    q[0] += bf2f(psa[0]);
                    q[1] += bf2f(psa[1]);
                    q[2] += bf2f(psa[2]);
                    q[3] += bf2f(psa[3]);
                    accv[0] += fmaxf(q[0], 0.f);
                    accv[1] += fmaxf(q[1], 0.f);
                    accv[2] += fmaxf(q[2], 0.f);
                    accv[3] += fmaxf(q[3], 0.f);

                    psa = psb; eva = evb;
                    psb = psn; evb = evn;
                }
            }

            const float idg = inv_deg[node];
            u16x4 o;
            o[0] = f2bf(accv[0] * idg);
            o[1] = f2bf(accv[1] * idg);
            o[2] = f2bf(accv[2] * idg);
            o[3] = f2bf(accv[3] * idg);
            *(u16x4*)(agg + (size_t)node * 256 + col) = o;
        }
    }
}

// out[node] = dot(h3[node,:], h2w) + h2b  — one wave per node
__global__ __launch_bounds__(256) void head_out(
    const u16* __restrict__ h3,
    const float* __restrict__ h2w,
    const float* __restrict__ h2b,
    float* __restrict__ out)
{
    const int node = (int)((blockIdx.x * 256 + threadIdx.x) >> 6);
    const int lane = threadIdx.x & 63;
    if (node >= NN) return;
    const int col = lane * 4;
    u16x4 hv = *(const u16x4*)(h3 + (size_t)node * 256 + col);
    float4 wv = *(const float4*)(h2w + col);
    float s = bf2f(hv[0]) * wv.x + bf2f(hv[1]) * wv.y +
              bf2f(hv[2]) * wv.z + bf2f(hv[3]) * wv.w;
    for (int off = 32; off > 0; off >>= 1)
        s += __shfl_down(s, off, 64);
    if (lane == 0) out[node] = s + h2b[0];
}

// ---------------- setup kernels ----------------
__global__ void zero_int(int* p, int n) {
    int i = blockIdx.x * 256 + threadIdx.x;
    if (i < n) p[i] = 0;
}

__global__ void hist_k(const int* __restrict__ ei, int* __restrict__ deg) {
    int e = blockIdx.x * 256 + threadIdx.x;
    if (e < NE) atomicAdd(&deg[ei[NE + e]], 1);
}

// phase 1: per-block sums of deg (coalesced)
__global__ __launch_bounds__(256) void block_sum_k(const int* __restrict__ deg,
                                                   int* __restrict__ bsum) {
    __shared__ int sm[4];
    const int i = blockIdx.x * 256 + threadIdx.x;
    int v = (i < NN) ? deg[i] : 0;
    for (int off = 32; off > 0; off >>= 1)
        v += __shfl_down(v, off, 64);
    const int lane = threadIdx.x & 63;
    const int w = threadIdx.x >> 6;
    if (lane == 0) sm[w] = v;
    __syncthreads();
    if (threadIdx.x == 0)
        bsum[blockIdx.x] = sm[0] + sm[1] + sm[2] + sm[3];
}

// phase 2: one small block scans NBLK block sums -> exclusive boff, total
__global__ __launch_bounds__(256) void scan_block_k(const int* __restrict__ bsum,
                                                    int* __restrict__ boff,
                                                    int* __restrict__ row_start) {
    __shared__ int sm[256];
    const int tid = threadIdx.x;
    int v = (tid < NBLK) ? bsum[tid] : 0;
    sm[tid] = v;
    __syncthreads();
    for (int o = 1; o < 256; o <<= 1) {
        int tv = (tid >= o) ? sm[tid - o] : 0;
        __syncthreads();
        sm[tid] += tv;
        __syncthreads();
    }
    if (tid < NBLK) boff[tid] = sm[tid] - v;  // exclusive
    if (tid == NBLK - 1) row_start[NN] = sm[tid];
}

// phase 3: per-block exclusive scan + block offset; coalesced writes.
// block 0 also zeroes the edge_agg work cursors.
__global__ __launch_bounds__(256) void writeback_k(const int* __restrict__ deg,
                                                   const int* __restrict__ boff,
                                                   int* __restrict__ row_start,
                                                   int* __restrict__ cursor,
                                                   float* __restrict__ inv_deg,
                                                   int* __restrict__ ctr) {
    __shared__ int sm[256];
    const int tid = threadIdx.x;
    const int i = blockIdx.x * 256 + tid;
    if (blockIdx.x == 0 && tid < 8) ctr[tid] = 0;
    int v = (i < NN) ? deg[i] : 0;
    sm[tid] = v;
    __syncthreads();
    for (int o = 1; o < 256; o <<= 1) {
        int tv = (tid >= o) ? sm[tid - o] : 0;
        __syncthreads();
        sm[tid] += tv;
        __syncthreads();
    }
    if (i < NN) {
        const int rs = boff[blockIdx.x] + sm[tid] - v;
        row_start[i] = rs;
        cursor[i]    = rs;
        inv_deg[i]   = 1.0f / fmaxf((float)v, 1.0f);
    }
}

__global__ void scatter_k(const int* __restrict__ ei, const float* __restrict__ eattr,
                          int* __restrict__ cursor, int* __restrict__ src_perm,
                          u32* __restrict__ eattr_p32) {
    int e = blockIdx.x * 256 + threadIdx.x;
    if (e >= NE) return;
    int s = ei[e], d = ei[NE + e];
    int pos = atomicAdd(&cursor[d], 1);
    src_perm[pos] = s;
    const float* sr = eattr + (size_t)e * 32;
    u32* dr = eattr_p32 + (size_t)pos * 16;
#pragma unroll
    for (int j = 0; j < 16; ++j)
        dr[j] = packh2(sr[2 * j], sr[2 * j + 1]);
}

// jobs: tr=1: dst[n*K+k] = bf16(src[k*256+n])
//       tr=2: We pack: dst32[kp*256+c] = packh2(src[2kp*256+c], src[(2kp+1)*256+c])
struct TJob { const float* src; u16* dst; int K; int ksh; int tr; };
struct TJobs { TJob j[16]; };

__global__ void transpose_k(TJobs jobs) {
    TJob jb = jobs.j[blockIdx.y];
    int idx = blockIdx.x * 256 + threadIdx.x;
    if (idx >= (jb.K << 8)) return;
    if (jb.tr == 1) {
        int n = idx >> jb.ksh;
        int k = idx & (jb.K - 1);
        jb.dst[idx] = f2bf(jb.src[k * 256 + n]);
    } else {
        int kp = idx >> 8;
        int c = idx & 255;
        ((u32*)jb.dst)[idx] = packh2(jb.src[(2 * kp) * 256 + c],
                                     jb.src[(2 * kp + 1) * 256 + c]);
    }
}

__global__ void cvt_f32_bf16(const float* __restrict__ src, u16* __restrict__ dst, int n) {
    int i = blockIdx.x * 256 + threadIdx.x;
    if (i < n) dst[i] = f2bf(src[i]);
}

// ---------------------------------------------------------------------------
extern "C" void kernel_launch(void* const* d_in, const int* in_sizes, int n_in,
                              void* d_out, int out_size, void* d_ws, size_t ws_size,
                              hipStream_t stream) {
    const float* x     = (const float*)d_in[0];
    const int*   ei    = (const int*)d_in[1];
    const float* eattr = (const float*)d_in[2];
    const float* e0_w  = (const float*)d_in[3];
    const float* e0_b  = (const float*)d_in[4];
    const float* n0_w  = (const float*)d_in[5];
    const float* n0_b  = (const float*)d_in[6];
    const float* e_w   = (const float*)d_in[7];
    const float* e_b   = (const float*)d_in[8];
    const float* n_w   = (const float*)d_in[9];
    const float* n_b   = (const float*)d_in[10];
    const float* h1_w  = (const float*)d_in[11];
    const float* h1_b  = (const float*)d_in[12];
    const float* h2_w  = (const float*)d_in[13];
    const float* h2_b  = (const float*)d_in[14];
    float* out = (float*)d_out;
    (void)in_sizes; (void)n_in; (void)out_size; (void)ws_size;

    char* base = (char*)d_ws;
    size_t off = 0;
    auto alloc = [&](size_t nbytes) -> void* {
        void* p = base + off;
        off += (nbytes + 255) & ~(size_t)255;
        return p;
    };

    int*   deg       = (int*)alloc(NN * 4);
    int*   row_start = (int*)alloc((NN + 1) * 4);
    int*   cursor    = (int*)alloc(NN * 4);
    float* invdeg    = (float*)alloc(NN * 4);
    int*   bsum      = (int*)alloc(NBLK * 4);
    int*   boff      = (int*)alloc(NBLK * 4);
    int*   ctr       = (int*)alloc(8 * 4);
    int*   src_perm  = (int*)alloc(NE * 4);
    u32*   eattr_p32 = (u32*)alloc((size_t)NE * 16 * 4);
    u16*   WcatT0    = (u16*)alloc(768 * 128 * 2);
    u16*   WcatT1    = (u16*)alloc(768 * 256 * 2);
    u16*   WcatT2    = (u16*)alloc(768 * 256 * 2);
    u32*   WePk0     = (u32*)alloc(16 * 256 * 4);
    u32*   WePk1     = (u32*)alloc(16 * 256 * 4);
    u32*   WePk2     = (u32*)alloc(16 * 256 * 4);
    u16*   NbT0      = (u16*)alloc(256 * 256 * 2);
    u16*   NbT1      = (u16*)alloc(256 * 256 * 2);
    u16*   NbT2      = (u16*)alloc(256 * 256 * 2);
    u16*   H1T       = (u16*)alloc(256 * 256 * 2);
    u16*   P         = (u16*)alloc((size_t)NN * 768 * 2);
    u16*   aggb      = (u16*)alloc((size_t)NN * 256 * 2);
    u16*   hb        = (u16*)alloc((size_t)NN * 256 * 2);
    u16*   xb        = aggb;  // alias: xb dead before aggb first written

    // ---- CSR build + weight prep ----
    zero_int<<<(NN + 255) / 256, 256, 0, stream>>>(deg, NN);
    hist_k<<<(NE + 255) / 256, 256, 0, stream>>>(ei, deg);
    block_sum_k<<<NBLK, 256, 0, stream>>>(deg, bsum);
    scan_block_k<<<1, 256, 0, stream>>>(bsum, boff, row_start);
    writeback_k<<<NBLK, 256, 0, stream>>>(deg, boff, row_start, cursor, invdeg, ctr);
    scatter_k<<<(NE + 255) / 256, 256, 0, stream>>>(ei, eattr, cursor, src_perm, eattr_p32);

    const float* ew2 = e_w + 544 * 256;
    const float* nw2 = n_w + 512 * 256;

    TJobs tj;
    auto setj = [&](int i, const float* s, void* d, int K, int tr) {
        tj.j[i].src = s; tj.j[i].dst = (u16*)d; tj.j[i].K = K; tj.j[i].tr = tr;
        tj.j[i].ksh = (K == 256) ? 8 : (K == 128 ? 7 : 5);
    };
    setj(0,  e0_w,             WcatT0,             128, 1);
    setj(1,  e0_w + 128 * 256, WcatT0 + 256 * 128, 128, 1);
    setj(2,  n0_w,             WcatT0 + 512 * 128, 128, 1);
    setj(3,  n0_w + 128 * 256, NbT0,               256, 1);
    setj(4,  e_w,              WcatT1,             256, 1);
    setj(5,  e_w + 256 * 256,  WcatT1 + 256 * 256, 256, 1);
    setj(6,  n_w,              WcatT1 + 512 * 256, 256, 1);
    setj(7,  n_w + 256 * 256,  NbT1,               256, 1);
    setj(8,  ew2,              WcatT2,             256, 1);
    setj(9,  ew2 + 256 * 256,  WcatT2 + 256 * 256, 256, 1);
    setj(10, nw2,              WcatT2 + 512 * 256, 256, 1);
    setj(11, nw2 + 256 * 256,  NbT2,               256, 1);
    setj(12, h1_w,             H1T,                256, 1);
    setj(13, e0_w + 256 * 256, WePk0,              16,  2);
    setj(14, e_w + 512 * 256,  WePk1,              16,  2);
    setj(15, ew2 + 512 * 256,  WePk2,              16,  2);
    transpose_k<<<dim3(256, 16), 256, 0, stream>>>(tj);

    cvt_f32_bf16<<<(NN * 128 + 255) / 256, 256, 0, stream>>>(x, xb, NN * 128);

    const int MT = (NN + 127) / 128;  // 391
    u16* WcatT[3] = {WcatT0, WcatT1, WcatT2};
    u32* WePk[3]  = {WePk0, WePk1, WePk2};
    u16* NbT[3]   = {NbT0, NbT1, NbT2};
    const float* ebs[3] = {e0_b, e_b, e_b + 256};
    const float* nbs[3] = {n0_b, n_b, n_b + 256};

    for (int l = 0; l < 3; ++l) {
        const u16* hin = (l == 0) ? xb : hb;
        const int kin = (l == 0) ? 128 : 256;
        // P = hin @ [Ws | Wd | ntop]   -> [NN, 768]
        gemm_bt<<<dim3(MT, 6), 256, 0, stream>>>(hin, kin, WcatT[l], P, 768, NN, kin,
                                                 nullptr, nullptr, 0, 0);
        // agg = mean_dst relu(Ps[src] + Pd[dst] + eattr@We + eb)
        // persistent, dynamic contiguous chunks
        edge_agg_fused<<<2048, 256, 0, stream>>>(P, eattr_p32, WePk[l], row_start,
                                                 src_perm, invdeg, ebs[l], aggb, ctr + l);
        // h = relu(agg @ nbot + R + nb)
        gemm_bt<<<dim3(MT, 2), 256, 0, stream>>>(aggb, 256, NbT[l], hb, 256, NN, 256,
                                                 nbs[l], P + 512, 768, 1);
    }
    // head: h3 = relu(h @ h1_w + h1_b); out = h3 @ h2_w + h2_b
    gemm_bt<<<dim3(MT, 2), 256, 0, stream>>>(hb, 256, H1T, aggb, 256, NN, 256,
                                             h1_b, nullptr, 0, 1);
    head_out<<<NN / 4, 256, 0, stream>>>(aggb, h2_w, h2_b, out);
}

// Round 7
// 999.114 us; speedup vs baseline: 1.2696x; 1.2696x over previous
//
#include <hip/hip_runtime.h>
#include <hip/hip_bf16.h>
#include <hip/hip_fp16.h>

#define NN 50000
#define NE 400000
#define NBLK 196   // ceil(NN/256)
#define NPW 2      // nodes per wave in edge_agg
#define QS_STRIDE 264  // 256 + 8 pad (LDS bank spread)

typedef unsigned short u16;
typedef unsigned int u32;
typedef __attribute__((ext_vector_type(8))) short short8;
typedef __attribute__((ext_vector_type(8))) _Float16 f16x8;
typedef __attribute__((ext_vector_type(4))) float f32x4;
typedef __attribute__((ext_vector_type(4))) unsigned short u16x4;

typedef __attribute__((address_space(1))) const void as1_void;
typedef __attribute__((address_space(3))) void as3_void;

static __device__ __forceinline__ float bf2f(u16 u) {
    return __uint_as_float(((u32)u) << 16);
}
static __device__ __forceinline__ u16 f2bf(float f) {
    u32 x = __float_as_uint(f);
    x += 0x7fffu + ((x >> 16) & 1u);
    return (u16)(x >> 16);
}
static __device__ __forceinline__ u16 f2h(float f) {
    return __half_as_ushort(__float2half(f));
}
static __device__ __forceinline__ float h2f(u16 u) {
    return __half2float(__ushort_as_half(u));
}

static __device__ __forceinline__ void gload_lds16(const u16* g, u16* l) {
    __builtin_amdgcn_global_load_lds((as1_void*)g, (as3_void*)l, 16, 0, 0);
}

// ---------------------------------------------------------------------------
// bf16 GEMM: C[M,N] = A[M,K] @ Bt[N,K]^T, epilogue (+bias)(+aux)(relu), bf16 out.
// m97 structure: 128x128 tile, BK=32, 4 waves, 4x4 16x16x32 frags.
// ---------------------------------------------------------------------------
__global__ __launch_bounds__(256) void gemm_bt(
    const u16* __restrict__ A, int lda,
    const u16* __restrict__ Bt,
    u16* __restrict__ C, int ldc,
    int M, int K,
    const float* __restrict__ bias,
    const u16* __restrict__ aux, int ld_aux,
    int relu)
{
    __shared__ u16 As[128 * 32];
    __shared__ u16 Bs[128 * 32];

    const int t = threadIdx.x;
    const int w = t >> 6;
    const int lane = t & 63;
    const int quad = lane >> 4;
    const int l15 = lane & 15;
    const int tile_m = blockIdx.x * 128;
    const int tile_n = blockIdx.y * 128;
    const int wm = (w >> 1) * 64;
    const int wn = (w & 1) * 64;

    f32x4 acc[4][4];
#pragma unroll
    for (int r = 0; r < 4; ++r)
#pragma unroll
        for (int c = 0; c < 4; ++c)
            acc[r][c] = (f32x4){0.f, 0.f, 0.f, 0.f};

    int ar0 = tile_m + (t >> 2);      if (ar0 > M - 1) ar0 = M - 1;
    int ar1 = tile_m + 64 + (t >> 2); if (ar1 > M - 1) ar1 = M - 1;
    const int br0 = tile_n + (t >> 2);
    const int br1 = tile_n + 64 + (t >> 2);
    const int koff = (t & 3) * 8;

    u16* lAs0 = As + w * 512;
    u16* lAs1 = As + 2048 + w * 512;
    u16* lBs0 = Bs + w * 512;
    u16* lBs1 = Bs + 2048 + w * 512;

    const u16* Arow0 = A + (size_t)ar0 * lda + koff;
    const u16* Arow1 = A + (size_t)ar1 * lda + koff;
    const u16* Brow0 = Bt + (size_t)br0 * K + koff;
    const u16* Brow1 = Bt + (size_t)br1 * K + koff;

    for (int k0 = 0; k0 < K; k0 += 32) {
        gload_lds16(Arow0 + k0, lAs0);
        gload_lds16(Arow1 + k0, lAs1);
        gload_lds16(Brow0 + k0, lBs0);
        gload_lds16(Brow1 + k0, lBs1);
        __syncthreads();

        short8 af[4], bfr[4];
#pragma unroll
        for (int r = 0; r < 4; ++r)
            af[r] = *(const short8*)&As[(wm + r * 16 + l15) * 32 + quad * 8];
#pragma unroll
        for (int c = 0; c < 4; ++c)
            bfr[c] = *(const short8*)&Bs[(wn + c * 16 + l15) * 32 + quad * 8];
#pragma unroll
        for (int r = 0; r < 4; ++r)
#pragma unroll
            for (int c = 0; c < 4; ++c)
                acc[r][c] = __builtin_amdgcn_mfma_f32_16x16x32_bf16(af[r], bfr[c], acc[r][c], 0, 0, 0);
        __syncthreads();
    }

#pragma unroll
    for (int r = 0; r < 4; ++r) {
#pragma unroll
        for (int c = 0; c < 4; ++c) {
            const int coln = tile_n + wn + c * 16 + l15;
            const float bv = bias ? bias[coln] : 0.0f;
#pragma unroll
            for (int i = 0; i < 4; ++i) {
                const int row = tile_m + wm + r * 16 + quad * 4 + i;
                if (row < M) {
                    float v = acc[r][c][i] + bv;
                    if (aux) v += bf2f(aux[(size_t)row * ld_aux + coln]);
                    if (relu) v = fmaxf(v, 0.f);
                    C[(size_t)row * ldc + coln] = f2bf(v);
                }
            }
        }
    }
}

// ---------------------------------------------------------------------------
// Fused edge message + mean aggregation.
// Q = eattr@We computed by MFMA over groups of 16 CSR-consecutive edges
// (f16 16x16x32, K=32 in one instruction), round-tripped through a per-wave
// LDS slice, then segmented epilogue: m = relu(Q + Ps[src] + Pd[node] + eb),
// agg = mean. One wave owns NPW consecutive nodes (contiguous CSR range).
// WeT: [256 cols][32 k] f16.  eattr_p: [NE][32] f16, CSR-permuted.
// P rows are [Ps(256) | Pd(256) | R(256)].
// ---------------------------------------------------------------------------
__global__ __launch_bounds__(256) void edge_agg_fused(
    const u16* __restrict__ P,
    const _Float16* __restrict__ eattr_p,
    const _Float16* __restrict__ WeT,
    const int* __restrict__ row_start,
    const int* __restrict__ src_perm,
    const float* __restrict__ inv_deg,
    const float* __restrict__ eb,
    u16* __restrict__ agg)
{
    __shared__ _Float16 Qs_all[4][16 * QS_STRIDE];

    const int wv = threadIdx.x >> 6;
    const int lane = threadIdx.x & 63;
    const int l15 = lane & 15;
    const int quad = lane >> 4;
    const int col = lane * 4;
    _Float16* Qs = Qs_all[wv];

    const int wid = blockIdx.x * 4 + wv;
    const int n0 = wid * NPW;
    if (n0 >= NN) return;
    const int n1 = (n0 + NPW < NN) ? n0 + NPW : NN;

    // preload B fragments: WeT[ct*16+l15][quad*8..+7], 16 col-tiles
    f16x8 bw[16];
#pragma unroll
    for (int ct = 0; ct < 16; ++ct)
        bw[ct] = *(const f16x8*)(WeT + (ct * 16 + l15) * 32 + quad * 8);

    const float4 ebv = *(const float4*)(eb + col);

    const int jbeg = row_start[n0];
    const int jend = row_start[n1];

    int node = n0;
    int s1 = row_start[node + 1];
    f32x4 accv = (f32x4){0.f, 0.f, 0.f, 0.f};
    u16x4 pdv = *(const u16x4*)(P + (size_t)node * 768 + 256 + col);
    f32x4 pb;
    pb[0] = bf2f(pdv[0]) + ebv.x;
    pb[1] = bf2f(pdv[1]) + ebv.y;
    pb[2] = bf2f(pdv[2]) + ebv.z;
    pb[3] = bf2f(pdv[3]) + ebv.w;

    for (int j0 = jbeg; j0 < jend; j0 += 16) {
        // ---- MFMA: Q for edges j0..j0+15 (tail rows junk, discarded) ----
        int ea = j0 + l15;
        if (ea > NE - 1) ea = NE - 1;
        f16x8 afr = *(const f16x8*)(eattr_p + (size_t)ea * 32 + quad * 8);
#pragma unroll
        for (int ct = 0; ct < 16; ++ct) {
            f32x4 qt = __builtin_amdgcn_mfma_f32_16x16x32_f16(
                afr, bw[ct], (f32x4){0.f, 0.f, 0.f, 0.f}, 0, 0, 0);
            // C-layout: row(edge)=quad*4+i, col=ct*16+l15
#pragma unroll
            for (int i = 0; i < 4; ++i)
                Qs[(quad * 4 + i) * QS_STRIDE + ct * 16 + l15] = (_Float16)qt[i];
        }
        // same-wave LDS producer/consumer: compiler inserts lgkmcnt waits

        int glen = jend - j0;
        if (glen > 16) glen = 16;
        for (int jj = 0; jj < glen; ++jj) {
            const int j = j0 + jj;
            while (j == s1) {  // flush finished node(s), incl. deg-0 nodes
                const float idg = inv_deg[node];
                u16x4 o;
                o[0] = f2bf(accv[0] * idg);
                o[1] = f2bf(accv[1] * idg);
                o[2] = f2bf(accv[2] * idg);
                o[3] = f2bf(accv[3] * idg);
                *(u16x4*)(agg + (size_t)node * 256 + col) = o;
                ++node;
                s1 = row_start[node + 1];
                accv = (f32x4){0.f, 0.f, 0.f, 0.f};
                pdv = *(const u16x4*)(P + (size_t)node * 768 + 256 + col);
                pb[0] = bf2f(pdv[0]) + ebv.x;
                pb[1] = bf2f(pdv[1]) + ebv.y;
                pb[2] = bf2f(pdv[2]) + ebv.z;
                pb[3] = bf2f(pdv[3]) + ebv.w;
            }
            const int s = src_perm[j];
            u16x4 ps = *(const u16x4*)(P + (size_t)s * 768 + col);
            u16x4 qv = *(const u16x4*)&Qs[jj * QS_STRIDE + col];
            f32x4 q;
            q[0] = pb[0] + h2f(qv[0]) + bf2f(ps[0]);
            q[1] = pb[1] + h2f(qv[1]) + bf2f(ps[1]);
            q[2] = pb[2] + h2f(qv[2]) + bf2f(ps[2]);
            q[3] = pb[3] + h2f(qv[3]) + bf2f(ps[3]);
            accv[0] += fmaxf(q[0], 0.f);
            accv[1] += fmaxf(q[1], 0.f);
            accv[2] += fmaxf(q[2], 0.f);
            accv[3] += fmaxf(q[3], 0.f);
        }
    }

    // trailing flush: current node + any trailing deg-0 nodes
    while (node < n1) {
        const float idg = inv_deg[node];
        u16x4 o;
        o[0] = f2bf(accv[0] * idg);
        o[1] = f2bf(accv[1] * idg);
        o[2] = f2bf(accv[2] * idg);
        o[3] = f2bf(accv[3] * idg);
        *(u16x4*)(agg + (size_t)node * 256 + col) = o;
        ++node;
        accv = (f32x4){0.f, 0.f, 0.f, 0.f};
    }
}

// out[node] = dot(h3[node,:], h2w) + h2b  — one wave per node
__global__ __launch_bounds__(256) void head_out(
    const u16* __restrict__ h3,
    const float* __restrict__ h2w,
    const float* __restrict__ h2b,
    float* __restrict__ out)
{
    const int node = (int)((blockIdx.x * 256 + threadIdx.x) >> 6);
    const int lane = threadIdx.x & 63;
    if (node >= NN) return;
    const int col = lane * 4;
    u16x4 hv = *(const u16x4*)(h3 + (size_t)node * 256 + col);
    float4 wv = *(const float4*)(h2w + col);
    float s = bf2f(hv[0]) * wv.x + bf2f(hv[1]) * wv.y +
              bf2f(hv[2]) * wv.z + bf2f(hv[3]) * wv.w;
    for (int off = 32; off > 0; off >>= 1)
        s += __shfl_down(s, off, 64);
    if (lane == 0) out[node] = s + h2b[0];
}

// ---------------- setup kernels ----------------
__global__ void zero_int(int* p, int n) {
    int i = blockIdx.x * 256 + threadIdx.x;
    if (i < n) p[i] = 0;
}

__global__ void hist_k(const int* __restrict__ ei, int* __restrict__ deg) {
    int e = blockIdx.x * 256 + threadIdx.x;
    if (e < NE) atomicAdd(&deg[ei[NE + e]], 1);
}

// phase 1: per-block sums of deg (coalesced)
__global__ __launch_bounds__(256) void block_sum_k(const int* __restrict__ deg,
                                                   int* __restrict__ bsum) {
    __shared__ int sm[4];
    const int i = blockIdx.x * 256 + threadIdx.x;
    int v = (i < NN) ? deg[i] : 0;
    for (int off = 32; off > 0; off >>= 1)
        v += __shfl_down(v, off, 64);
    const int lane = threadIdx.x & 63;
    const int w = threadIdx.x >> 6;
    if (lane == 0) sm[w] = v;
    __syncthreads();
    if (threadIdx.x == 0)
        bsum[blockIdx.x] = sm[0] + sm[1] + sm[2] + sm[3];
}

// phase 2: one small block scans NBLK block sums -> exclusive boff, total
__global__ __launch_bounds__(256) void scan_block_k(const int* __restrict__ bsum,
                                                    int* __restrict__ boff,
                                                    int* __restrict__ row_start) {
    __shared__ int sm[256];
    const int tid = threadIdx.x;
    int v = (tid < NBLK) ? bsum[tid] : 0;
    sm[tid] = v;
    __syncthreads();
    for (int o = 1; o < 256; o <<= 1) {
        int tv = (tid >= o) ? sm[tid - o] : 0;
        __syncthreads();
        sm[tid] += tv;
        __syncthreads();
    }
    if (tid < NBLK) boff[tid] = sm[tid] - v;  // exclusive
    if (tid == NBLK - 1) row_start[NN] = sm[tid];
}

// phase 3: per-block exclusive scan + block offset; coalesced writes
__global__ __launch_bounds__(256) void writeback_k(const int* __restrict__ deg,
                                                   const int* __restrict__ boff,
                                                   int* __restrict__ row_start,
                                                   int* __restrict__ cursor,
                                                   float* __restrict__ inv_deg) {
    __shared__ int sm[256];
    const int tid = threadIdx.x;
    const int i = blockIdx.x * 256 + tid;
    int v = (i < NN) ? deg[i] : 0;
    sm[tid] = v;
    __syncthreads();
    for (int o = 1; o < 256; o <<= 1) {
        int tv = (tid >= o) ? sm[tid - o] : 0;
        __syncthreads();
        sm[tid] += tv;
        __syncthreads();
    }
    if (i < NN) {
        const int rs = boff[blockIdx.x] + sm[tid] - v;
        row_start[i] = rs;
        cursor[i]    = rs;
        inv_deg[i]   = 1.0f / fmaxf((float)v, 1.0f);
    }
}

__global__ void scatter_k(const int* __restrict__ ei, const float* __restrict__ eattr,
                          int* __restrict__ cursor, int* __restrict__ src_perm,
                          u16* __restrict__ eattr_p) {
    int e = blockIdx.x * 256 + threadIdx.x;
    if (e >= NE) return;
    int s = ei[e], d = ei[NE + e];
    int pos = atomicAdd(&cursor[d], 1);
    src_perm[pos] = s;
    const float* sr = eattr + (size_t)e * 32;
    u16* dr = eattr_p + (size_t)pos * 32;
#pragma unroll
    for (int j = 0; j < 32; ++j)
        dr[j] = f2h(sr[j]);
}

// jobs: tr=1: dst[n*K+k] = bf16(src[k*256+n])   (Bt for gemm)
//       tr=3: WeT f16: dst[c*32+k] = f16(src[k*256+c]), K=32
struct TJob { const float* src; u16* dst; int K; int ksh; int tr; };
struct TJobs { TJob j[16]; };

__global__ void transpose_k(TJobs jobs) {
    TJob jb = jobs.j[blockIdx.y];
    int idx = blockIdx.x * 256 + threadIdx.x;
    if (idx >= (jb.K << 8)) return;
    if (jb.tr == 1) {
        int n = idx >> jb.ksh;
        int k = idx & (jb.K - 1);
        jb.dst[idx] = f2bf(jb.src[k * 256 + n]);
    } else {
        int c = idx >> 5;
        int k = idx & 31;
        jb.dst[idx] = f2h(jb.src[k * 256 + c]);
    }
}

__global__ void cvt_f32_bf16(const float* __restrict__ src, u16* __restrict__ dst, int n) {
    int i = blockIdx.x * 256 + threadIdx.x;
    if (i < n) dst[i] = f2bf(src[i]);
}

// ---------------------------------------------------------------------------
extern "C" void kernel_launch(void* const* d_in, const int* in_sizes, int n_in,
                              void* d_out, int out_size, void* d_ws, size_t ws_size,
                              hipStream_t stream) {
    const float* x     = (const float*)d_in[0];
    const int*   ei    = (const int*)d_in[1];
    const float* eattr = (const float*)d_in[2];
    const float* e0_w  = (const float*)d_in[3];
    const float* e0_b  = (const float*)d_in[4];
    const float* n0_w  = (const float*)d_in[5];
    const float* n0_b  = (const float*)d_in[6];
    const float* e_w   = (const float*)d_in[7];
    const float* e_b   = (const float*)d_in[8];
    const float* n_w   = (const float*)d_in[9];
    const float* n_b   = (const float*)d_in[10];
    const float* h1_w  = (const float*)d_in[11];
    const float* h1_b  = (const float*)d_in[12];
    const float* h2_w  = (const float*)d_in[13];
    const float* h2_b  = (const float*)d_in[14];
    float* out = (float*)d_out;
    (void)in_sizes; (void)n_in; (void)out_size; (void)ws_size;

    char* base = (char*)d_ws;
    size_t off = 0;
    auto alloc = [&](size_t nbytes) -> void* {
        void* p = base + off;
        off += (nbytes + 255) & ~(size_t)255;
        return p;
    };

    int*   deg       = (int*)alloc(NN * 4);
    int*   row_start = (int*)alloc((NN + 1) * 4);
    int*   cursor    = (int*)alloc(NN * 4);
    float* invdeg    = (float*)alloc(NN * 4);
    int*   bsum      = (int*)alloc(NBLK * 4);
    int*   boff      = (int*)alloc(NBLK * 4);
    int*   src_perm  = (int*)alloc(NE * 4);
    u16*   eattr_p   = (u16*)alloc((size_t)NE * 32 * 2);
    u16*   WcatT0    = (u16*)alloc(768 * 128 * 2);
    u16*   WcatT1    = (u16*)alloc(768 * 256 * 2);
    u16*   WcatT2    = (u16*)alloc(768 * 256 * 2);
    u16*   WeT0      = (u16*)alloc(256 * 32 * 2);
    u16*   WeT1      = (u16*)alloc(256 * 32 * 2);
    u16*   WeT2      = (u16*)alloc(256 * 32 * 2);
    u16*   NbT0      = (u16*)alloc(256 * 256 * 2);
    u16*   NbT1      = (u16*)alloc(256 * 256 * 2);
    u16*   NbT2      = (u16*)alloc(256 * 256 * 2);
    u16*   H1T       = (u16*)alloc(256 * 256 * 2);
    u16*   P         = (u16*)alloc((size_t)NN * 768 * 2);
    u16*   aggb      = (u16*)alloc((size_t)NN * 256 * 2);
    u16*   hb        = (u16*)alloc((size_t)NN * 256 * 2);
    u16*   xb        = aggb;  // alias: xb dead before aggb first written

    // ---- CSR build + weight prep ----
    zero_int<<<(NN + 255) / 256, 256, 0, stream>>>(deg, NN);
    hist_k<<<(NE + 255) / 256, 256, 0, stream>>>(ei, deg);
    block_sum_k<<<NBLK, 256, 0, stream>>>(deg, bsum);
    scan_block_k<<<1, 256, 0, stream>>>(bsum, boff, row_start);
    writeback_k<<<NBLK, 256, 0, stream>>>(deg, boff, row_start, cursor, invdeg);
    scatter_k<<<(NE + 255) / 256, 256, 0, stream>>>(ei, eattr, cursor, src_perm, eattr_p);

    const float* ew2 = e_w + 544 * 256;
    const float* nw2 = n_w + 512 * 256;

    TJobs tj;
    auto setj = [&](int i, const float* s, void* d, int K, int tr) {
        tj.j[i].src = s; tj.j[i].dst = (u16*)d; tj.j[i].K = K; tj.j[i].tr = tr;
        tj.j[i].ksh = (K == 256) ? 8 : (K == 128 ? 7 : 5);
    };
    setj(0,  e0_w,             WcatT0,             128, 1);
    setj(1,  e0_w + 128 * 256, WcatT0 + 256 * 128, 128, 1);
    setj(2,  n0_w,             WcatT0 + 512 * 128, 128, 1);
    setj(3,  n0_w + 128 * 256, NbT0,               256, 1);
    setj(4,  e_w,              WcatT1,             256, 1);
    setj(5,  e_w + 256 * 256,  WcatT1 + 256 * 256, 256, 1);
    setj(6,  n_w,              WcatT1 + 512 * 256, 256, 1);
    setj(7,  n_w + 256 * 256,  NbT1,               256, 1);
    setj(8,  ew2,              WcatT2,             256, 1);
    setj(9,  ew2 + 256 * 256,  WcatT2 + 256 * 256, 256, 1);
    setj(10, nw2,              WcatT2 + 512 * 256, 256, 1);
    setj(11, nw2 + 256 * 256,  NbT2,               256, 1);
    setj(12, h1_w,             H1T,                256, 1);
    setj(13, e0_w + 256 * 256, WeT0,               32,  3);
    setj(14, e_w + 512 * 256,  WeT1,               32,  3);
    setj(15, ew2 + 512 * 256,  WeT2,               32,  3);
    transpose_k<<<dim3(256, 16), 256, 0, stream>>>(tj);

    cvt_f32_bf16<<<(NN * 128 + 255) / 256, 256, 0, stream>>>(x, xb, NN * 128);

    const int MT = (NN + 127) / 128;  // 391
    const int AGG_BLOCKS = ((NN + NPW - 1) / NPW + 3) / 4;  // 6250
    u16* WcatT[3] = {WcatT0, WcatT1, WcatT2};
    u16* WeT[3]   = {WeT0, WeT1, WeT2};
    u16* NbT[3]   = {NbT0, NbT1, NbT2};
    const float* ebs[3] = {e0_b, e_b, e_b + 256};
    const float* nbs[3] = {n0_b, n_b, n_b + 256};

    for (int l = 0; l < 3; ++l) {
        const u16* hin = (l == 0) ? xb : hb;
        const int kin = (l == 0) ? 128 : 256;
        // P = hin @ [Ws | Wd | ntop]   -> [NN, 768]
        gemm_bt<<<dim3(MT, 6), 256, 0, stream>>>(hin, kin, WcatT[l], P, 768, NN, kin,
                                                 nullptr, nullptr, 0, 0);
        // agg = mean_dst relu(Ps[src] + Pd[dst] + eattr@We + eb)  [MFMA Q]
        edge_agg_fused<<<AGG_BLOCKS, 256, 0, stream>>>(
            P, (const _Float16*)eattr_p, (const _Float16*)WeT[l],
            row_start, src_perm, invdeg, ebs[l], aggb);
        // h = relu(agg @ nbot + R + nb)
        gemm_bt<<<dim3(MT, 2), 256, 0, stream>>>(aggb, 256, NbT[l], hb, 256, NN, 256,
                                                 nbs[l], P + 512, 768, 1);
    }
    // head: h3 = relu(h @ h1_w + h1_b); out = h3 @ h2_w + h2_b
    gemm_bt<<<dim3(MT, 2), 256, 0, stream>>>(hb, 256, H1T, aggb, 256, NN, 256,
                                             h1_b, nullptr, 0, 1);
    head_out<<<NN / 4, 256, 0, stream>>>(aggb, h2_w, h2_b, out);
}

// Round 8
// 870.277 us; speedup vs baseline: 1.4575x; 1.1480x over previous
//
#include <hip/hip_runtime.h>
#include <hip/hip_bf16.h>
#include <hip/hip_fp16.h>

#define NN 50000
#define NE 400000
#define NBLK 196   // ceil(NN/256)

typedef unsigned short u16;
typedef unsigned int u32;
typedef __attribute__((ext_vector_type(8))) short short8;
typedef __attribute__((ext_vector_type(4))) float f32x4;
typedef __attribute__((ext_vector_type(4))) unsigned short u16x4;
typedef __attribute__((ext_vector_type(2))) _Float16 h2;

typedef __attribute__((address_space(1))) const void as1_void;
typedef __attribute__((address_space(3))) void as3_void;

static __device__ __forceinline__ float bf2f(u16 u) {
    return __uint_as_float(((u32)u) << 16);
}
static __device__ __forceinline__ u16 f2bf(float f) {
    u32 x = __float_as_uint(f);
    x += 0x7fffu + ((x >> 16) & 1u);
    return (u16)(x >> 16);
}
static __device__ __forceinline__ u32 packh2(float a, float b) {
    return ((u32)__half_as_ushort(__float2half(b)) << 16) |
           (u32)__half_as_ushort(__float2half(a));
}
static __device__ __forceinline__ float fdot2u(u32 a, u32 b, float c) {
    return __builtin_amdgcn_fdot2(__builtin_bit_cast(h2, a),
                                  __builtin_bit_cast(h2, b), c, false);
}

static __device__ __forceinline__ void gload_lds16(const u16* g, u16* l) {
    __builtin_amdgcn_global_load_lds((as1_void*)g, (as3_void*)l, 16, 0, 0);
}

// ---------------------------------------------------------------------------
// bf16 GEMM: C[M,N] = A[M,K] @ Bt[N,K]^T, epilogue (+bias)(relu), bf16 out.
// m97 structure: 128x128 tile, BK=32, 4 waves, 4x4 16x16x32 frags.
// gridDim.y*128 must equal N; M guarded (loads clamped, stores masked).
// ---------------------------------------------------------------------------
__global__ __launch_bounds__(256) void gemm_bt(
    const u16* __restrict__ A, int lda,
    const u16* __restrict__ Bt,
    u16* __restrict__ C, int ldc,
    int M, int K,
    const float* __restrict__ bias,
    int relu)
{
    __shared__ u16 As[128 * 32];
    __shared__ u16 Bs[128 * 32];

    const int t = threadIdx.x;
    const int w = t >> 6;
    const int lane = t & 63;
    const int quad = lane >> 4;
    const int l15 = lane & 15;
    const int tile_m = blockIdx.x * 128;
    const int tile_n = blockIdx.y * 128;
    const int wm = (w >> 1) * 64;
    const int wn = (w & 1) * 64;

    f32x4 acc[4][4];
#pragma unroll
    for (int r = 0; r < 4; ++r)
#pragma unroll
        for (int c = 0; c < 4; ++c)
            acc[r][c] = (f32x4){0.f, 0.f, 0.f, 0.f};

    int ar0 = tile_m + (t >> 2);      if (ar0 > M - 1) ar0 = M - 1;
    int ar1 = tile_m + 64 + (t >> 2); if (ar1 > M - 1) ar1 = M - 1;
    const int br0 = tile_n + (t >> 2);
    const int br1 = tile_n + 64 + (t >> 2);
    const int koff = (t & 3) * 8;

    u16* lAs0 = As + w * 512;
    u16* lAs1 = As + 2048 + w * 512;
    u16* lBs0 = Bs + w * 512;
    u16* lBs1 = Bs + 2048 + w * 512;

    const u16* Arow0 = A + (size_t)ar0 * lda + koff;
    const u16* Arow1 = A + (size_t)ar1 * lda + koff;
    const u16* Brow0 = Bt + (size_t)br0 * K + koff;
    const u16* Brow1 = Bt + (size_t)br1 * K + koff;

    for (int k0 = 0; k0 < K; k0 += 32) {
        gload_lds16(Arow0 + k0, lAs0);
        gload_lds16(Arow1 + k0, lAs1);
        gload_lds16(Brow0 + k0, lBs0);
        gload_lds16(Brow1 + k0, lBs1);
        __syncthreads();

        short8 af[4], bfr[4];
#pragma unroll
        for (int r = 0; r < 4; ++r)
            af[r] = *(const short8*)&As[(wm + r * 16 + l15) * 32 + quad * 8];
#pragma unroll
        for (int c = 0; c < 4; ++c)
            bfr[c] = *(const short8*)&Bs[(wn + c * 16 + l15) * 32 + quad * 8];
#pragma unroll
        for (int r = 0; r < 4; ++r)
#pragma unroll
            for (int c = 0; c < 4; ++c)
                acc[r][c] = __builtin_amdgcn_mfma_f32_16x16x32_bf16(af[r], bfr[c], acc[r][c], 0, 0, 0);
        __syncthreads();
    }

#pragma unroll
    for (int r = 0; r < 4; ++r) {
#pragma unroll
        for (int c = 0; c < 4; ++c) {
            const int coln = tile_n + wn + c * 16 + l15;
            const float bv = bias ? bias[coln] : 0.0f;
#pragma unroll
            for (int i = 0; i < 4; ++i) {
                const int row = tile_m + wm + r * 16 + quad * 4 + i;
                if (row < M) {
                    float v = acc[r][c][i] + bv;
                    if (relu) v = fmaxf(v, 0.f);
                    C[(size_t)row * ldc + coln] = f2bf(v);
                }
            }
        }
    }
}

// ---------------------------------------------------------------------------
// Fused edge message + mean aggregation (round-4 structure, eb pre-folded
// into Pd by the P-GEMM bias). One wave per node; edges CSR-sorted by dst.
// P rows are [Ps(256) | Pd(256)], stride 512. agg written into Z[:,0:256].
// ---------------------------------------------------------------------------
__global__ __launch_bounds__(256) void edge_agg_fused(
    const u16* __restrict__ P,
    const u32* __restrict__ eattr_p32,
    const u32* __restrict__ WePk,
    const int* __restrict__ row_start,
    const int* __restrict__ src_perm,
    const float* __restrict__ inv_deg,
    u16* __restrict__ aggZ)
{
    const int node = (int)((blockIdx.x * 256 + threadIdx.x) >> 6);
    const int lane = threadIdx.x & 63;
    const int l15 = lane & 15;
    const int col = lane * 4;
    if (node >= NN) return;

    // this lane's 4 columns of We, packed f16 pairs: 16 kpairs x uint4
    uint4 wpk[16];
#pragma unroll
    for (int kp = 0; kp < 16; ++kp)
        wpk[kp] = *(const uint4*)(WePk + kp * 256 + col);

    u16x4 pdv = *(const u16x4*)(P + (size_t)node * 512 + 256 + col);
    f32x4 pb;
    pb[0] = bf2f(pdv[0]);
    pb[1] = bf2f(pdv[1]);
    pb[2] = bf2f(pdv[2]);
    pb[3] = bf2f(pdv[3]);

    f32x4 accv = (f32x4){0.f, 0.f, 0.f, 0.f};
    const int s0r = row_start[node], s1r = row_start[node + 1];

    if (s1r > s0r) {
        const int jlast = s1r - 1;
        int j1 = (s0r + 1 < jlast) ? s0r + 1 : jlast;
        int sa = src_perm[s0r];
        int sb = src_perm[j1];
        u16x4 psa = *(const u16x4*)(P + (size_t)sa * 512 + col);
        u16x4 psb = *(const u16x4*)(P + (size_t)sb * 512 + col);
        u32 eva = eattr_p32[(size_t)s0r * 16 + l15];
        u32 evb = eattr_p32[(size_t)j1 * 16 + l15];

        for (int j = s0r; j < s1r; ++j) {
            int jc = (j + 2 < jlast) ? j + 2 : jlast;
            int sn = src_perm[jc];
            u16x4 psn = *(const u16x4*)(P + (size_t)sn * 512 + col);
            u32 evn = eattr_p32[(size_t)jc * 16 + l15];

            f32x4 q = pb;
#pragma unroll
            for (int kp = 0; kp < 16; ++kp) {
                u32 evk = (u32)__builtin_amdgcn_readlane((int)eva, kp);
                q[0] = fdot2u(evk, wpk[kp].x, q[0]);
                q[1] = fdot2u(evk, wpk[kp].y, q[1]);
                q[2] = fdot2u(evk, wpk[kp].z, q[2]);
                q[3] = fdot2u(evk, wpk[kp].w, q[3]);
            }
            q[0] += bf2f(psa[0]);
            q[1] += bf2f(psa[1]);
            q[2] += bf2f(psa[2]);
            q[3] += bf2f(psa[3]);
            accv[0] += fmaxf(q[0], 0.f);
            accv[1] += fmaxf(q[1], 0.f);
            accv[2] += fmaxf(q[2], 0.f);
            accv[3] += fmaxf(q[3], 0.f);

            psa = psb; eva = evb;
            psb = psn; evb = evn;
        }
    }

    const float idg = inv_deg[node];
    u16x4 o;
    o[0] = f2bf(accv[0] * idg);
    o[1] = f2bf(accv[1] * idg);
    o[2] = f2bf(accv[2] * idg);
    o[3] = f2bf(accv[3] * idg);
    *(u16x4*)(aggZ + (size_t)node * 512 + col) = o;
}

// out[node] = dot(h4[node,:], h2w) + h2b  — one wave per node; h4 in Z[:,0:256]
__global__ __launch_bounds__(256) void head_out(
    const u16* __restrict__ h4Z,
    const float* __restrict__ h2w,
    const float* __restrict__ h2b,
    float* __restrict__ out)
{
    const int node = (int)((blockIdx.x * 256 + threadIdx.x) >> 6);
    const int lane = threadIdx.x & 63;
    if (node >= NN) return;
    const int col = lane * 4;
    u16x4 hv = *(const u16x4*)(h4Z + (size_t)node * 512 + col);
    float4 wv = *(const float4*)(h2w + col);
    float s = bf2f(hv[0]) * wv.x + bf2f(hv[1]) * wv.y +
              bf2f(hv[2]) * wv.z + bf2f(hv[3]) * wv.w;
    for (int off = 32; off > 0; off >>= 1)
        s += __shfl_down(s, off, 64);
    if (lane == 0) out[node] = s + h2b[0];
}

// ---------------- setup kernels ----------------
__global__ void zero_int(int* p, int n) {
    int i = blockIdx.x * 256 + threadIdx.x;
    if (i < n) p[i] = 0;
}

__global__ void hist_k(const int* __restrict__ ei, int* __restrict__ deg) {
    int e = blockIdx.x * 256 + threadIdx.x;
    if (e < NE) atomicAdd(&deg[ei[NE + e]], 1);
}

__global__ __launch_bounds__(256) void block_sum_k(const int* __restrict__ deg,
                                                   int* __restrict__ bsum) {
    __shared__ int sm[4];
    const int i = blockIdx.x * 256 + threadIdx.x;
    int v = (i < NN) ? deg[i] : 0;
    for (int off = 32; off > 0; off >>= 1)
        v += __shfl_down(v, off, 64);
    const int lane = threadIdx.x & 63;
    const int w = threadIdx.x >> 6;
    if (lane == 0) sm[w] = v;
    __syncthreads();
    if (threadIdx.x == 0)
        bsum[blockIdx.x] = sm[0] + sm[1] + sm[2] + sm[3];
}

__global__ __launch_bounds__(256) void scan_block_k(const int* __restrict__ bsum,
                                                    int* __restrict__ boff,
                                                    int* __restrict__ row_start) {
    __shared__ int sm[256];
    const int tid = threadIdx.x;
    int v = (tid < NBLK) ? bsum[tid] : 0;
    sm[tid] = v;
    __syncthreads();
    for (int o = 1; o < 256; o <<= 1) {
        int tv = (tid >= o) ? sm[tid - o] : 0;
        __syncthreads();
        sm[tid] += tv;
        __syncthreads();
    }
    if (tid < NBLK) boff[tid] = sm[tid] - v;  // exclusive
    if (tid == NBLK - 1) row_start[NN] = sm[tid];
}

__global__ __launch_bounds__(256) void writeback_k(const int* __restrict__ deg,
                                                   const int* __restrict__ boff,
                                                   int* __restrict__ row_start,
                                                   int* __restrict__ cursor,
                                                   float* __restrict__ inv_deg) {
    __shared__ int sm[256];
    const int tid = threadIdx.x;
    const int i = blockIdx.x * 256 + tid;
    int v = (i < NN) ? deg[i] : 0;
    sm[tid] = v;
    __syncthreads();
    for (int o = 1; o < 256; o <<= 1) {
        int tv = (tid >= o) ? sm[tid - o] : 0;
        __syncthreads();
        sm[tid] += tv;
        __syncthreads();
    }
    if (i < NN) {
        const int rs = boff[blockIdx.x] + sm[tid] - v;
        row_start[i] = rs;
        cursor[i]    = rs;
        inv_deg[i]   = 1.0f / fmaxf((float)v, 1.0f);
    }
}

__global__ void scatter_k(const int* __restrict__ ei, const float* __restrict__ eattr,
                          int* __restrict__ cursor, int* __restrict__ src_perm,
                          u32* __restrict__ eattr_p32) {
    int e = blockIdx.x * 256 + threadIdx.x;
    if (e >= NE) return;
    int s = ei[e], d = ei[NE + e];
    int pos = atomicAdd(&cursor[d], 1);
    src_perm[pos] = s;
    const float* sr = eattr + (size_t)e * 32;
    u32* dr = eattr_p32 + (size_t)pos * 16;
#pragma unroll
    for (int j = 0; j < 16; ++j)
        dr[j] = packh2(sr[2 * j], sr[2 * j + 1]);
}

// P-GEMM bias: [512] f32 per layer = [0(256) | eb(256)]
__global__ void bias_build(const float* __restrict__ e0b,
                           const float* __restrict__ eb1,
                           const float* __restrict__ eb2,
                           float* __restrict__ dst) {
    int i = blockIdx.x * 256 + threadIdx.x;
    if (i >= 1536) return;
    int l = i >> 9, c = i & 511;
    const float* s = (l == 0) ? e0b : (l == 1) ? eb1 : eb2;
    dst[i] = (c < 256) ? 0.f : s[c - 256];
}

// jobs: tr=1: dst[n*dstride+k] = bf16(src[k*256+n]), n in 0..255, k in 0..K-1
//       tr=2: We pack u32: dst32[kp*256+c] = packh2(src[2kp*256+c], src[(2kp+1)*256+c])
struct TJob { const float* src; u16* dst; int K; int ksh; int tr; int dstride; };
struct TJobs { TJob j[16]; };

__global__ void transpose_k(TJobs jobs) {
    TJob jb = jobs.j[blockIdx.y];
    int idx = blockIdx.x * 256 + threadIdx.x;
    if (idx >= (jb.K << 8)) return;
    if (jb.tr == 1) {
        int n = idx >> jb.ksh;
        int k = idx & (jb.K - 1);
        jb.dst[n * jb.dstride + k] = f2bf(jb.src[k * 256 + n]);
    } else {
        int kp = idx >> 8;
        int c = idx & 255;
        ((u32*)jb.dst)[idx] = packh2(jb.src[(2 * kp) * 256 + c],
                                     jb.src[(2 * kp + 1) * 256 + c]);
    }
}

// x (f32 [NN,128]) -> Z[:,256:384] bf16 (row stride 512)
__global__ void cvt_x(const float* __restrict__ src, u16* __restrict__ Z) {
    int i = blockIdx.x * 256 + threadIdx.x;
    if (i >= NN * 128) return;
    int n = i >> 7, c = i & 127;
    Z[(size_t)n * 512 + 256 + c] = f2bf(src[i]);
}

// ---------------------------------------------------------------------------
extern "C" void kernel_launch(void* const* d_in, const int* in_sizes, int n_in,
                              void* d_out, int out_size, void* d_ws, size_t ws_size,
                              hipStream_t stream) {
    const float* x     = (const float*)d_in[0];
    const int*   ei    = (const int*)d_in[1];
    const float* eattr = (const float*)d_in[2];
    const float* e0_w  = (const float*)d_in[3];
    const float* e0_b  = (const float*)d_in[4];
    const float* n0_w  = (const float*)d_in[5];
    const float* n0_b  = (const float*)d_in[6];
    const float* e_w   = (const float*)d_in[7];
    const float* e_b   = (const float*)d_in[8];
    const float* n_w   = (const float*)d_in[9];
    const float* n_b   = (const float*)d_in[10];
    const float* h1_w  = (const float*)d_in[11];
    const float* h1_b  = (const float*)d_in[12];
    const float* h2_w  = (const float*)d_in[13];
    const float* h2_b  = (const float*)d_in[14];
    float* out = (float*)d_out;
    (void)in_sizes; (void)n_in; (void)out_size; (void)ws_size;

    char* base = (char*)d_ws;
    size_t off = 0;
    auto alloc = [&](size_t nbytes) -> void* {
        void* p = base + off;
        off += (nbytes + 255) & ~(size_t)255;
        return p;
    };

    int*   deg       = (int*)alloc(NN * 4);
    int*   row_start = (int*)alloc((NN + 1) * 4);
    int*   cursor    = (int*)alloc(NN * 4);
    float* invdeg    = (float*)alloc(NN * 4);
    int*   bsum      = (int*)alloc(NBLK * 4);
    int*   boff      = (int*)alloc(NBLK * 4);
    int*   src_perm  = (int*)alloc(NE * 4);
    u32*   eattr_p32 = (u32*)alloc((size_t)NE * 16 * 4);
    u16*   WcatT0    = (u16*)alloc(512 * 128 * 2);
    u16*   WcatT1    = (u16*)alloc(512 * 256 * 2);
    u16*   WcatT2    = (u16*)alloc(512 * 256 * 2);
    u32*   WePk0     = (u32*)alloc(16 * 256 * 4);
    u32*   WePk1     = (u32*)alloc(16 * 256 * 4);
    u32*   WePk2     = (u32*)alloc(16 * 256 * 4);
    u16*   BcatT0    = (u16*)alloc(256 * 384 * 2);
    u16*   BcatT1    = (u16*)alloc(256 * 512 * 2);
    u16*   BcatT2    = (u16*)alloc(256 * 512 * 2);
    u16*   H1T       = (u16*)alloc(256 * 256 * 2);
    float* bias512   = (float*)alloc(3 * 512 * 4);
    u16*   P         = (u16*)alloc((size_t)NN * 512 * 2);
    u16*   Z0        = (u16*)alloc((size_t)NN * 512 * 2);
    u16*   Z1        = (u16*)alloc((size_t)NN * 512 * 2);

    // ---- CSR build + weight prep ----
    zero_int<<<(NN + 255) / 256, 256, 0, stream>>>(deg, NN);
    hist_k<<<(NE + 255) / 256, 256, 0, stream>>>(ei, deg);
    block_sum_k<<<NBLK, 256, 0, stream>>>(deg, bsum);
    scan_block_k<<<1, 256, 0, stream>>>(bsum, boff, row_start);
    writeback_k<<<NBLK, 256, 0, stream>>>(deg, boff, row_start, cursor, invdeg);
    scatter_k<<<(NE + 255) / 256, 256, 0, stream>>>(ei, eattr, cursor, src_perm, eattr_p32);
    bias_build<<<6, 256, 0, stream>>>(e0_b, e_b, e_b + 256, bias512);

    const float* ew2 = e_w + 544 * 256;
    const float* nw2 = n_w + 512 * 256;

    TJobs tj;
    auto setj = [&](int i, const float* s, void* d, int K, int tr, int dstride) {
        tj.j[i].src = s; tj.j[i].dst = (u16*)d; tj.j[i].K = K; tj.j[i].tr = tr;
        tj.j[i].dstride = dstride;
        tj.j[i].ksh = (K == 256) ? 8 : (K == 128 ? 7 : 5);
    };
    // P-GEMM weights: WcatT[n(512)][K] = [Ws rows | Wd rows] transposed
    setj(0,  e0_w,             WcatT0,             128, 1, 128);  // Ws, n 0..255
    setj(1,  e0_w + 128 * 256, WcatT0 + 256 * 128, 128, 1, 128);  // Wd, n 256..511
    setj(2,  e_w,              WcatT1,             256, 1, 256);
    setj(3,  e_w + 256 * 256,  WcatT1 + 256 * 256, 256, 1, 256);
    setj(4,  ew2,              WcatT2,             256, 1, 256);
    setj(5,  ew2 + 256 * 256,  WcatT2 + 256 * 256, 256, 1, 256);
    // node-GEMM weights: BcatT[n(256)][k] = [nbot(k<256) | ntop]
    setj(6,  n0_w + 128 * 256, BcatT0,             256, 1, 384);  // nbot (agg part)
    setj(7,  n0_w,             BcatT0 + 256,       128, 1, 384);  // ntop (x part, k 256..383)
    setj(8,  n_w + 256 * 256,  BcatT1,             256, 1, 512);
    setj(9,  n_w,              BcatT1 + 256,       256, 1, 512);
    setj(10, nw2 + 256 * 256,  BcatT2,             256, 1, 512);
    setj(11, nw2,              BcatT2 + 256,       256, 1, 512);
    setj(12, h1_w,             H1T,                256, 1, 256);
    // edge-attr weights, packed f16 pairs
    setj(13, e0_w + 256 * 256, WePk0,              16,  2, 0);
    setj(14, e_w + 512 * 256,  WePk1,              16,  2, 0);
    setj(15, ew2 + 512 * 256,  WePk2,              16,  2, 0);
    transpose_k<<<dim3(256, 16), 256, 0, stream>>>(tj);

    cvt_x<<<(NN * 128 + 255) / 256, 256, 0, stream>>>(x, Z0);

    const int MT = (NN + 127) / 128;  // 391
    u16* WcatT[3] = {WcatT0, WcatT1, WcatT2};
    u32* WePk[3]  = {WePk0, WePk1, WePk2};
    u16* BcatT[3] = {BcatT0, BcatT1, BcatT2};
    const float* nbs[3] = {n0_b, n_b, n_b + 256};
    // ping-pong: layer l reads h from Zin[:,256:512], writes agg to Zin[:,0:256],
    // node-GEMM reads Zin[:, 0:K] and writes h' to Zout[:,256:512]
    u16* Zin[3]  = {Z0, Z1, Z0};
    u16* Zout[3] = {Z1, Z0, Z1};
    const int kin[3]  = {128, 256, 256};  // h width into P-GEMM
    const int knode[3] = {384, 512, 512}; // [agg|h] width into node-GEMM

    for (int l = 0; l < 3; ++l) {
        // P = h @ [Ws | Wd] + [0|eb]  -> [NN, 512]
        gemm_bt<<<dim3(MT, 4), 256, 0, stream>>>(Zin[l] + 256, 512, WcatT[l], P, 512,
                                                 NN, kin[l], bias512 + l * 512, 0);
        // agg = mean_dst relu(Ps[src] + Pd[dst] + eattr@We)  (eb folded into Pd)
        edge_agg_fused<<<NN / 4, 256, 0, stream>>>(P, eattr_p32, WePk[l], row_start,
                                                   src_perm, invdeg, Zin[l]);
        // h' = relu([agg | h] @ [nbot; ntop] + nb)
        gemm_bt<<<dim3(MT, 2), 256, 0, stream>>>(Zin[l], 512, BcatT[l], Zout[l] + 256, 512,
                                                 NN, knode[l], nbs[l], 1);
    }
    // head: h4 = relu(h3 @ h1_w + h1_b) -> Z1[:,0:256]; out = h4 @ h2_w + h2_b
    gemm_bt<<<dim3(MT, 2), 256, 0, stream>>>(Z1 + 256, 512, H1T, Z1, 512,
                                             NN, 256, h1_b, 1);
    head_out<<<NN / 4, 256, 0, stream>>>(Z1, h2_w, h2_b, out);
}

// Round 10
// 854.928 us; speedup vs baseline: 1.4837x; 1.0180x over previous
//
#include <hip/hip_runtime.h>
#include <hip/hip_bf16.h>
#include <hip/hip_fp16.h>

#define NN 50000
#define NE 400000
#define NBLK 196   // ceil(NN/256)
#define PST 544    // P row stride (1088 B = 64*17, breaks power-of-2 aliasing)

typedef unsigned short u16;
typedef unsigned int u32;
typedef __attribute__((ext_vector_type(8))) short short8;
typedef __attribute__((ext_vector_type(4))) float f32x4;
typedef __attribute__((ext_vector_type(4))) unsigned short u16x4;
typedef __attribute__((ext_vector_type(2))) _Float16 h2;

typedef __attribute__((address_space(1))) const void as1_void;
typedef __attribute__((address_space(3))) void as3_void;

static __device__ __forceinline__ float bf2f(u16 u) {
    return __uint_as_float(((u32)u) << 16);
}
static __device__ __forceinline__ float bf2f_lo(u32 u) {
    return __uint_as_float(u << 16);
}
static __device__ __forceinline__ float bf2f_hi(u32 u) {
    return __uint_as_float(u & 0xffff0000u);
}
static __device__ __forceinline__ u16 f2bf(float f) {
    u32 x = __float_as_uint(f);
    x += 0x7fffu + ((x >> 16) & 1u);
    return (u16)(x >> 16);
}
static __device__ __forceinline__ u32 packbf2(float a, float b) {
    return ((u32)f2bf(b) << 16) | (u32)f2bf(a);
}
static __device__ __forceinline__ u32 packh2(float a, float b) {
    return ((u32)__half_as_ushort(__float2half(b)) << 16) |
           (u32)__half_as_ushort(__float2half(a));
}
static __device__ __forceinline__ float fdot2u(u32 a, u32 b, float c) {
    return __builtin_amdgcn_fdot2(__builtin_bit_cast(h2, a),
                                  __builtin_bit_cast(h2, b), c, false);
}

static __device__ __forceinline__ void gload_lds16(const u16* g, u16* l) {
    __builtin_amdgcn_global_load_lds((as1_void*)g, (as3_void*)l, 16, 0, 0);
}

// ---------------------------------------------------------------------------
// bf16 GEMM: C[M,N] = A[M,K] @ Bt[N,K]^T, epilogue (+bias)(relu), bf16 out.
// m97 structure: 128x128 tile, BK=32, 4 waves, 4x4 16x16x32 frags.
// ---------------------------------------------------------------------------
__global__ __launch_bounds__(256) void gemm_bt(
    const u16* __restrict__ A, int lda,
    const u16* __restrict__ Bt,
    u16* __restrict__ C, int ldc,
    int M, int K,
    const float* __restrict__ bias,
    int relu)
{
    __shared__ u16 As[128 * 32];
    __shared__ u16 Bs[128 * 32];

    const int t = threadIdx.x;
    const int w = t >> 6;
    const int lane = t & 63;
    const int quad = lane >> 4;
    const int l15 = lane & 15;
    const int tile_m = blockIdx.x * 128;
    const int tile_n = blockIdx.y * 128;
    const int wm = (w >> 1) * 64;
    const int wn = (w & 1) * 64;

    f32x4 acc[4][4];
#pragma unroll
    for (int r = 0; r < 4; ++r)
#pragma unroll
        for (int c = 0; c < 4; ++c)
            acc[r][c] = (f32x4){0.f, 0.f, 0.f, 0.f};

    int ar0 = tile_m + (t >> 2);      if (ar0 > M - 1) ar0 = M - 1;
    int ar1 = tile_m + 64 + (t >> 2); if (ar1 > M - 1) ar1 = M - 1;
    const int br0 = tile_n + (t >> 2);
    const int br1 = tile_n + 64 + (t >> 2);
    const int koff = (t & 3) * 8;

    u16* lAs0 = As + w * 512;
    u16* lAs1 = As + 2048 + w * 512;
    u16* lBs0 = Bs + w * 512;
    u16* lBs1 = Bs + 2048 + w * 512;

    const u16* Arow0 = A + (size_t)ar0 * lda + koff;
    const u16* Arow1 = A + (size_t)ar1 * lda + koff;
    const u16* Brow0 = Bt + (size_t)br0 * K + koff;
    const u16* Brow1 = Bt + (size_t)br1 * K + koff;

    for (int k0 = 0; k0 < K; k0 += 32) {
        gload_lds16(Arow0 + k0, lAs0);
        gload_lds16(Arow1 + k0, lAs1);
        gload_lds16(Brow0 + k0, lBs0);
        gload_lds16(Brow1 + k0, lBs1);
        __syncthreads();

        short8 af[4], bfr[4];
#pragma unroll
        for (int r = 0; r < 4; ++r)
            af[r] = *(const short8*)&As[(wm + r * 16 + l15) * 32 + quad * 8];
#pragma unroll
        for (int c = 0; c < 4; ++c)
            bfr[c] = *(const short8*)&Bs[(wn + c * 16 + l15) * 32 + quad * 8];
#pragma unroll
        for (int r = 0; r < 4; ++r)
#pragma unroll
            for (int c = 0; c < 4; ++c)
                acc[r][c] = __builtin_amdgcn_mfma_f32_16x16x32_bf16(af[r], bfr[c], acc[r][c], 0, 0, 0);
        __syncthreads();
    }

#pragma unroll
    for (int r = 0; r < 4; ++r) {
#pragma unroll
        for (int c = 0; c < 4; ++c) {
            const int coln = tile_n + wn + c * 16 + l15;
            const float bv = bias ? bias[coln] : 0.0f;
#pragma unroll
            for (int i = 0; i < 4; ++i) {
                const int row = tile_m + wm + r * 16 + quad * 4 + i;
                if (row < M) {
                    float v = acc[r][c][i] + bv;
                    if (relu) v = fmaxf(v, 0.f);
                    C[(size_t)row * ldc + coln] = f2bf(v);
                }
            }
        }
    }
}

// ---------------------------------------------------------------------------
// Fused edge message + mean aggregation. TWO waves per node, 128 cols each
// (2 cols/lane as packed-bf16 u32). eb pre-folded into Pd via P-GEMM bias.
// P rows [Ps(256)|Pd(256)], stride PST. agg -> Z[:,0:256] (stride 512).
// ---------------------------------------------------------------------------
__global__ __launch_bounds__(256) void edge_agg_fused(
    const u16* __restrict__ P,
    const u32* __restrict__ eattr_p32,
    const u32* __restrict__ WePk,
    const int* __restrict__ row_start,
    const int* __restrict__ src_perm,
    const float* __restrict__ inv_deg,
    u16* __restrict__ aggZ)
{
    const int wid = (int)((blockIdx.x * 256 + threadIdx.x) >> 6);
    const int node = wid >> 1;
    const int half = wid & 1;
    const int lane = threadIdx.x & 63;
    const int l15 = lane & 15;
    const int coff = half * 128 + lane * 2;
    if (node >= NN) return;

    // this lane's 2 columns of We, packed f16 kpairs: 16 x uint2
    uint2 wk[16];
#pragma unroll
    for (int kp = 0; kp < 16; ++kp)
        wk[kp] = *(const uint2*)(WePk + kp * 256 + coff);

    const u32 pdu = *(const u32*)(P + (size_t)node * PST + 256 + coff);
    const float pb0 = bf2f_lo(pdu);
    const float pb1 = bf2f_hi(pdu);

    float acc0 = 0.f, acc1 = 0.f;
    const int s0r = row_start[node], s1r = row_start[node + 1];

    if (s1r > s0r) {
        const int jlast = s1r - 1;
        int j1 = (s0r + 1 < jlast) ? s0r + 1 : jlast;
        int sa = src_perm[s0r];
        int sb = src_perm[j1];
        u32 psa = *(const u32*)(P + (size_t)sa * PST + coff);
        u32 psb = *(const u32*)(P + (size_t)sb * PST + coff);
        u32 eva = eattr_p32[(size_t)s0r * 16 + l15];
        u32 evb = eattr_p32[(size_t)j1 * 16 + l15];

        for (int j = s0r; j < s1r; ++j) {
            int jc = (j + 2 < jlast) ? j + 2 : jlast;
            int sn = src_perm[jc];
            u32 psn = *(const u32*)(P + (size_t)sn * PST + coff);
            u32 evn = eattr_p32[(size_t)jc * 16 + l15];

            float q0 = pb0, q1 = pb1;
#pragma unroll
            for (int kp = 0; kp < 16; ++kp) {
                u32 evk = (u32)__builtin_amdgcn_readlane((int)eva, kp);
                q0 = fdot2u(evk, wk[kp].x, q0);
                q1 = fdot2u(evk, wk[kp].y, q1);
            }
            q0 += bf2f_lo(psa);
            q1 += bf2f_hi(psa);
            acc0 += fmaxf(q0, 0.f);
            acc1 += fmaxf(q1, 0.f);

            psa = psb; eva = evb;
            psb = psn; evb = evn;
        }
    }

    const float idg = inv_deg[node];
    *(u32*)(aggZ + (size_t)node * 512 + coff) = packbf2(acc0 * idg, acc1 * idg);
}

// out[node] = dot(h4[node,:], h2w) + h2b  — one wave per node; h4 in Z[:,0:256]
__global__ __launch_bounds__(256) void head_out(
    const u16* __restrict__ h4Z,
    const float* __restrict__ h2w,
    const float* __restrict__ h2b,
    float* __restrict__ out)
{
    const int node = (int)((blockIdx.x * 256 + threadIdx.x) >> 6);
    const int lane = threadIdx.x & 63;
    if (node >= NN) return;
    const int col = lane * 4;
    u16x4 hv = *(const u16x4*)(h4Z + (size_t)node * 512 + col);
    float4 wv = *(const float4*)(h2w + col);
    float s = bf2f(hv[0]) * wv.x + bf2f(hv[1]) * wv.y +
              bf2f(hv[2]) * wv.z + bf2f(hv[3]) * wv.w;
    for (int off = 32; off > 0; off >>= 1)
        s += __shfl_down(s, off, 64);
    if (lane == 0) out[node] = s + h2b[0];
}

// ---------------- setup kernels ----------------
__global__ void zero_int(int* p, int n) {
    int i = blockIdx.x * 256 + threadIdx.x;
    if (i < n) p[i] = 0;
}

__global__ void hist_k(const int* __restrict__ ei, int* __restrict__ deg) {
    int e = blockIdx.x * 256 + threadIdx.x;
    if (e < NE) atomicAdd(&deg[ei[NE + e]], 1);
}

__global__ __launch_bounds__(256) void block_sum_k(const int* __restrict__ deg,
                                                   int* __restrict__ bsum) {
    __shared__ int sm[4];
    const int i = blockIdx.x * 256 + threadIdx.x;
    int v = (i < NN) ? deg[i] : 0;
    for (int off = 32; off > 0; off >>= 1)
        v += __shfl_down(v, off, 64);
    const int lane = threadIdx.x & 63;
    const int w = threadIdx.x >> 6;
    if (lane == 0) sm[w] = v;
    __syncthreads();
    if (threadIdx.x == 0)
        bsum[blockIdx.x] = sm[0] + sm[1] + sm[2] + sm[3];
}

__global__ __launch_bounds__(256) void scan_block_k(const int* __restrict__ bsum,
                                                    int* __restrict__ boff,
                                                    int* __restrict__ row_start) {
    __shared__ int sm[256];
    const int tid = threadIdx.x;
    int v = (tid < NBLK) ? bsum[tid] : 0;
    sm[tid] = v;
    __syncthreads();
    for (int o = 1; o < 256; o <<= 1) {
        int tv = (tid >= o) ? sm[tid - o] : 0;
        __syncthreads();
        sm[tid] += tv;
        __syncthreads();
    }
    if (tid < NBLK) boff[tid] = sm[tid] - v;  // exclusive
    if (tid == NBLK - 1) row_start[NN] = sm[tid];
}

__global__ __launch_bounds__(256) void writeback_k(const int* __restrict__ deg,
                                                   const int* __restrict__ boff,
                                                   int* __restrict__ row_start,
                                                   int* __restrict__ cursor,
                                                   float* __restrict__ inv_deg) {
    __shared__ int sm[256];
    const int tid = threadIdx.x;
    const int i = blockIdx.x * 256 + tid;
    int v = (i < NN) ? deg[i] : 0;
    sm[tid] = v;
    __syncthreads();
    for (int o = 1; o < 256; o <<= 1) {
        int tv = (tid >= o) ? sm[tid - o] : 0;
        __syncthreads();
        sm[tid] += tv;
        __syncthreads();
    }
    if (i < NN) {
        const int rs = boff[blockIdx.x] + sm[tid] - v;
        row_start[i] = rs;
        cursor[i]    = rs;
        inv_deg[i]   = 1.0f / fmaxf((float)v, 1.0f);
    }
}

__global__ void scatter_k(const int* __restrict__ ei, const float* __restrict__ eattr,
                          int* __restrict__ cursor, int* __restrict__ src_perm,
                          u32* __restrict__ eattr_p32) {
    int e = blockIdx.x * 256 + threadIdx.x;
    if (e >= NE) return;
    int s = ei[e], d = ei[NE + e];
    int pos = atomicAdd(&cursor[d], 1);
    src_perm[pos] = s;
    const float* sr = eattr + (size_t)e * 32;
    u32 pk[16];
#pragma unroll
    for (int j = 0; j < 16; ++j)
        pk[j] = packh2(sr[2 * j], sr[2 * j + 1]);
    uint4* dr = (uint4*)(eattr_p32 + (size_t)pos * 16);
    dr[0] = (uint4){pk[0], pk[1], pk[2], pk[3]};
    dr[1] = (uint4){pk[4], pk[5], pk[6], pk[7]};
    dr[2] = (uint4){pk[8], pk[9], pk[10], pk[11]};
    dr[3] = (uint4){pk[12], pk[13], pk[14], pk[15]};
}

// P-GEMM bias: [512] f32 per layer = [0(256) | eb(256)]
__global__ void bias_build(const float* __restrict__ e0b,
                           const float* __restrict__ eb1,
                           const float* __restrict__ eb2,
                           float* __restrict__ dst) {
    int i = blockIdx.x * 256 + threadIdx.x;
    if (i >= 1536) return;
    int l = i >> 9, c = i & 511;
    const float* s = (l == 0) ? e0b : (l == 1) ? eb1 : eb2;
    dst[i] = (c < 256) ? 0.f : s[c - 256];
}

// jobs: tr=1: dst[n*dstride+k] = bf16(src[k*256+n]), n in 0..255, k in 0..K-1
//       tr=2: We pack u32: dst32[kp*256+c] = packh2(src[2kp*256+c], src[(2kp+1)*256+c])
struct TJob { const float* src; u16* dst; int K; int ksh; int tr; int dstride; };
struct TJobs { TJob j[16]; };

__global__ void transpose_k(TJobs jobs) {
    TJob jb = jobs.j[blockIdx.y];
    int idx = blockIdx.x * 256 + threadIdx.x;
    if (idx >= (jb.K << 8)) return;
    if (jb.tr == 1) {
        int n = idx >> jb.ksh;
        int k = idx & (jb.K - 1);
        jb.dst[n * jb.dstride + k] = f2bf(jb.src[k * 256 + n]);
    } else {
        int kp = idx >> 8;
        int c = idx & 255;
        ((u32*)jb.dst)[idx] = packh2(jb.src[(2 * kp) * 256 + c],
                                     jb.src[(2 * kp + 1) * 256 + c]);
    }
}

// x (f32 [NN,128]) -> Z[:,256:384] bf16 (row stride 512)
__global__ void cvt_x(const float* __restrict__ src, u16* __restrict__ Z) {
    int i = blockIdx.x * 256 + threadIdx.x;
    if (i >= NN * 128) return;
    int n = i >> 7, c = i & 127;
    Z[(size_t)n * 512 + 256 + c] = f2bf(src[i]);
}

// ---------------------------------------------------------------------------
extern "C" void kernel_launch(void* const* d_in, const int* in_sizes, int n_in,
                              void* d_out, int out_size, void* d_ws, size_t ws_size,
                              hipStream_t stream) {
    const float* x     = (const float*)d_in[0];
    const int*   ei    = (const int*)d_in[1];
    const float* eattr = (const float*)d_in[2];
    const float* e0_w  = (const float*)d_in[3];
    const float* e0_b  = (const float*)d_in[4];
    const float* n0_w  = (const float*)d_in[5];
    const float* n0_b  = (const float*)d_in[6];
    const float* e_w   = (const float*)d_in[7];
    const float* e_b   = (const float*)d_in[8];
    const float* n_w   = (const float*)d_in[9];
    const float* n_b   = (const float*)d_in[10];
    const float* h1_w  = (const float*)d_in[11];
    const float* h1_b  = (const float*)d_in[12];
    const float* h2_w  = (const float*)d_in[13];
    const float* h2_b  = (const float*)d_in[14];
    float* out = (float*)d_out;
    (void)in_sizes; (void)n_in; (void)out_size; (void)ws_size;

    char* base = (char*)d_ws;
    size_t off = 0;
    auto alloc = [&](size_t nbytes) -> void* {
        void* p = base + off;
        off += (nbytes + 255) & ~(size_t)255;
        return p;
    };

    int*   deg       = (int*)alloc(NN * 4);
    int*   row_start = (int*)alloc((NN + 1) * 4);
    int*   cursor    = (int*)alloc(NN * 4);
    float* invdeg    = (float*)alloc(NN * 4);
    int*   bsum      = (int*)alloc(NBLK * 4);
    int*   boff      = (int*)alloc(NBLK * 4);
    int*   src_perm  = (int*)alloc(NE * 4);
    u32*   eattr_p32 = (u32*)alloc((size_t)NE * 16 * 4);
    u16*   WcatT0    = (u16*)alloc(512 * 128 * 2);
    u16*   WcatT1    = (u16*)alloc(512 * 256 * 2);
    u16*   WcatT2    = (u16*)alloc(512 * 256 * 2);
    u32*   WePk0     = (u32*)alloc(16 * 256 * 4);
    u32*   WePk1     = (u32*)alloc(16 * 256 * 4);
    u32*   WePk2     = (u32*)alloc(16 * 256 * 4);
    u16*   BcatT0    = (u16*)alloc(256 * 384 * 2);
    u16*   BcatT1    = (u16*)alloc(256 * 512 * 2);
    u16*   BcatT2    = (u16*)alloc(256 * 512 * 2);
    u16*   H1T       = (u16*)alloc(256 * 256 * 2);
    float* bias512   = (float*)alloc(3 * 512 * 4);
    u16*   P         = (u16*)alloc((size_t)NN * PST * 2);
    u16*   Z0        = (u16*)alloc((size_t)NN * 512 * 2);
    u16*   Z1        = (u16*)alloc((size_t)NN * 512 * 2);

    // ---- CSR build + weight prep ----
    zero_int<<<(NN + 255) / 256, 256, 0, stream>>>(deg, NN);
    hist_k<<<(NE + 255) / 256, 256, 0, stream>>>(ei, deg);
    block_sum_k<<<NBLK, 256, 0, stream>>>(deg, bsum);
    scan_block_k<<<1, 256, 0, stream>>>(bsum, boff, row_start);
    writeback_k<<<NBLK, 256, 0, stream>>>(deg, boff, row_start, cursor, invdeg);
    scatter_k<<<(NE + 255) / 256, 256, 0, stream>>>(ei, eattr, cursor, src_perm, eattr_p32);
    bias_build<<<6, 256, 0, stream>>>(e0_b, e_b, e_b + 256, bias512);

    const float* ew2 = e_w + 544 * 256;
    const float* nw2 = n_w + 512 * 256;

    TJobs tj;
    auto setj = [&](int i, const float* s, void* d, int K, int tr, int dstride) {
        tj.j[i].src = s; tj.j[i].dst = (u16*)d; tj.j[i].K = K; tj.j[i].tr = tr;
        tj.j[i].dstride = dstride;
        tj.j[i].ksh = (K == 256) ? 8 : (K == 128 ? 7 : 5);
    };
    // P-GEMM weights: WcatT[n(512)][K] = [Ws rows | Wd rows] transposed
    setj(0,  e0_w,             WcatT0,             128, 1, 128);
    setj(1,  e0_w + 128 * 256, WcatT0 + 256 * 128, 128, 1, 128);
    setj(2,  e_w,              WcatT1,             256, 1, 256);
    setj(3,  e_w + 256 * 256,  WcatT1 + 256 * 256, 256, 1, 256);
    setj(4,  ew2,              WcatT2,             256, 1, 256);
    setj(5,  ew2 + 256 * 256,  WcatT2 + 256 * 256, 256, 1, 256);
    // node-GEMM weights: BcatT[n(256)][k] = [nbot(k<256) | ntop]
    setj(6,  n0_w + 128 * 256, BcatT0,             256, 1, 384);
    setj(7,  n0_w,             BcatT0 + 256,       128, 1, 384);
    setj(8,  n_w + 256 * 256,  BcatT1,             256, 1, 512);
    setj(9,  n_w,              BcatT1 + 256,       256, 1, 512);
    setj(10, nw2 + 256 * 256,  BcatT2,             256, 1, 512);
    setj(11, nw2,              BcatT2 + 256,       256, 1, 512);
    setj(12, h1_w,             H1T,                256, 1, 256);
    // edge-attr weights, packed f16 pairs
    setj(13, e0_w + 256 * 256, WePk0,              16,  2, 0);
    setj(14, e_w + 512 * 256,  WePk1,              16,  2, 0);
    setj(15, ew2 + 512 * 256,  WePk2,              16,  2, 0);
    transpose_k<<<dim3(256, 16), 256, 0, stream>>>(tj);

    cvt_x<<<(NN * 128 + 255) / 256, 256, 0, stream>>>(x, Z0);

    const int MT = (NN + 127) / 128;  // 391
    const int AGG_BLK = (2 * NN) / 4;  // 2 waves/node, 4 waves/block = 25000
    u16* WcatT[3] = {WcatT0, WcatT1, WcatT2};
    u32* WePk[3]  = {WePk0, WePk1, WePk2};
    u16* BcatT[3] = {BcatT0, BcatT1, BcatT2};
    const float* nbs[3] = {n0_b, n_b, n_b + 256};
    u16* Zin[3]  = {Z0, Z1, Z0};
    u16* Zout[3] = {Z1, Z0, Z1};
    const int kin[3]   = {128, 256, 256};
    const int knode[3] = {384, 512, 512};

    for (int l = 0; l < 3; ++l) {
        // P = h @ [Ws | Wd] + [0|eb]  -> [NN, 512] (stride PST)
        gemm_bt<<<dim3(MT, 4), 256, 0, stream>>>(Zin[l] + 256, 512, WcatT[l], P, PST,
                                                 NN, kin[l], bias512 + l * 512, 0);
        // agg = mean_dst relu(Ps[src] + Pd[dst] + eattr@We)
        edge_agg_fused<<<AGG_BLK, 256, 0, stream>>>(P, eattr_p32, WePk[l], row_start,
                                                    src_perm, invdeg, Zin[l]);
        // h' = relu([agg | h] @ [nbot; ntop] + nb)
        gemm_bt<<<dim3(MT, 2), 256, 0, stream>>>(Zin[l], 512, BcatT[l], Zout[l] + 256, 512,
                                                 NN, knode[l], nbs[l], 1);
    }
    // head: h4 = relu(h3 @ h1_w + h1_b) -> Z1[:,0:256]; out = h4 @ h2_w + h2_b
    gemm_bt<<<dim3(MT, 2), 256, 0, stream>>>(Z1 + 256, 512, H1T, Z1, 512,
                                             NN, 256, h1_b, 1);
    head_out<<<NN / 4, 256, 0, stream>>>(Z1, h2_w, h2_b, out);
}

// Round 11
// 786.699 us; speedup vs baseline: 1.6124x; 1.0867x over previous
//
#include <hip/hip_runtime.h>
#include <hip/hip_bf16.h>
#include <hip/hip_fp16.h>

#define NN 50000
#define NE 400000
#define NBLK 196   // ceil(NN/256)
#define PST 544    // P row stride (1088 B = 64*17, breaks power-of-2 aliasing)

typedef unsigned short u16;
typedef unsigned int u32;
typedef __attribute__((ext_vector_type(8))) short short8;
typedef __attribute__((ext_vector_type(4))) float f32x4;
typedef __attribute__((ext_vector_type(4))) unsigned short u16x4;
typedef __attribute__((ext_vector_type(2))) _Float16 h2;

typedef __attribute__((address_space(1))) const void as1_void;
typedef __attribute__((address_space(3))) void as3_void;

static __device__ __forceinline__ float bf2f(u16 u) {
    return __uint_as_float(((u32)u) << 16);
}
static __device__ __forceinline__ float bf2f_lo(u32 u) {
    return __uint_as_float(u << 16);
}
static __device__ __forceinline__ float bf2f_hi(u32 u) {
    return __uint_as_float(u & 0xffff0000u);
}
static __device__ __forceinline__ u16 f2bf(float f) {
    u32 x = __float_as_uint(f);
    x += 0x7fffu + ((x >> 16) & 1u);
    return (u16)(x >> 16);
}
static __device__ __forceinline__ u32 packbf2(float a, float b) {
    return ((u32)f2bf(b) << 16) | (u32)f2bf(a);
}
static __device__ __forceinline__ u32 packh2(float a, float b) {
    return ((u32)__half_as_ushort(__float2half(b)) << 16) |
           (u32)__half_as_ushort(__float2half(a));
}
static __device__ __forceinline__ float fdot2u(u32 a, u32 b, float c) {
    return __builtin_amdgcn_fdot2(__builtin_bit_cast(h2, a),
                                  __builtin_bit_cast(h2, b), c, false);
}

static __device__ __forceinline__ void gload_lds16(const u16* g, u16* l) {
    __builtin_amdgcn_global_load_lds((as1_void*)g, (as3_void*)l, 16, 0, 0);
}

// ---------------------------------------------------------------------------
// bf16 GEMM: C[M,N] = A[M,K] @ Bt[N,K]^T, epilogue (+bias)(relu), bf16 out.
// m97 structure: 128x128 tile, BK=32, 4 waves, 4x4 16x16x32 frags.
// ---------------------------------------------------------------------------
__global__ __launch_bounds__(256) void gemm_bt(
    const u16* __restrict__ A, int lda,
    const u16* __restrict__ Bt,
    u16* __restrict__ C, int ldc,
    int M, int K,
    const float* __restrict__ bias,
    int relu)
{
    __shared__ u16 As[128 * 32];
    __shared__ u16 Bs[128 * 32];

    const int t = threadIdx.x;
    const int w = t >> 6;
    const int lane = t & 63;
    const int quad = lane >> 4;
    const int l15 = lane & 15;
    const int tile_m = blockIdx.x * 128;
    const int tile_n = blockIdx.y * 128;
    const int wm = (w >> 1) * 64;
    const int wn = (w & 1) * 64;

    f32x4 acc[4][4];
#pragma unroll
    for (int r = 0; r < 4; ++r)
#pragma unroll
        for (int c = 0; c < 4; ++c)
            acc[r][c] = (f32x4){0.f, 0.f, 0.f, 0.f};

    int ar0 = tile_m + (t >> 2);      if (ar0 > M - 1) ar0 = M - 1;
    int ar1 = tile_m + 64 + (t >> 2); if (ar1 > M - 1) ar1 = M - 1;
    const int br0 = tile_n + (t >> 2);
    const int br1 = tile_n + 64 + (t >> 2);
    const int koff = (t & 3) * 8;

    u16* lAs0 = As + w * 512;
    u16* lAs1 = As + 2048 + w * 512;
    u16* lBs0 = Bs + w * 512;
    u16* lBs1 = Bs + 2048 + w * 512;

    const u16* Arow0 = A + (size_t)ar0 * lda + koff;
    const u16* Arow1 = A + (size_t)ar1 * lda + koff;
    const u16* Brow0 = Bt + (size_t)br0 * K + koff;
    const u16* Brow1 = Bt + (size_t)br1 * K + koff;

    for (int k0 = 0; k0 < K; k0 += 32) {
        gload_lds16(Arow0 + k0, lAs0);
        gload_lds16(Arow1 + k0, lAs1);
        gload_lds16(Brow0 + k0, lBs0);
        gload_lds16(Brow1 + k0, lBs1);
        __syncthreads();

        short8 af[4], bfr[4];
#pragma unroll
        for (int r = 0; r < 4; ++r)
            af[r] = *(const short8*)&As[(wm + r * 16 + l15) * 32 + quad * 8];
#pragma unroll
        for (int c = 0; c < 4; ++c)
            bfr[c] = *(const short8*)&Bs[(wn + c * 16 + l15) * 32 + quad * 8];
#pragma unroll
        for (int r = 0; r < 4; ++r)
#pragma unroll
            for (int c = 0; c < 4; ++c)
                acc[r][c] = __builtin_amdgcn_mfma_f32_16x16x32_bf16(af[r], bfr[c], acc[r][c], 0, 0, 0);
        __syncthreads();
    }

#pragma unroll
    for (int r = 0; r < 4; ++r) {
#pragma unroll
        for (int c = 0; c < 4; ++c) {
            const int coln = tile_n + wn + c * 16 + l15;
            const float bv = bias ? bias[coln] : 0.0f;
#pragma unroll
            for (int i = 0; i < 4; ++i) {
                const int row = tile_m + wm + r * 16 + quad * 4 + i;
                if (row < M) {
                    float v = acc[r][c][i] + bv;
                    if (relu) v = fmaxf(v, 0.f);
                    C[(size_t)row * ldc + coln] = f2bf(v);
                }
            }
        }
    }
}

// ---------------------------------------------------------------------------
// Fused edge message + mean aggregation. TWO waves per node, 128 cols each
// (2 cols/lane as packed-bf16 u32). Edge index j is wave-uniform: eattr and
// src_perm are fetched via readfirstlane-forced SCALAR loads (s_load, scalar
// pipe) so the VALU pipe only runs the 32 fdot2 + epilogue per edge.
// P rows [Ps(256)|Pd(256)], stride PST. agg -> Z[:,0:256] (stride 512).
// ---------------------------------------------------------------------------
__global__ __launch_bounds__(256) void edge_agg_fused(
    const u16* __restrict__ P,
    const u32* __restrict__ eattr_p32,
    const u32* __restrict__ WePk,
    const int* __restrict__ row_start,
    const int* __restrict__ src_perm,
    const float* __restrict__ inv_deg,
    u16* __restrict__ aggZ)
{
    const int wid = (int)((blockIdx.x * 256 + threadIdx.x) >> 6);
    const int node = wid >> 1;
    const int half = wid & 1;
    const int lane = threadIdx.x & 63;
    const int coff = half * 128 + lane * 2;
    if (node >= NN) return;

    // this lane's 2 columns of We, packed f16 kpairs: 16 x uint2
    uint2 wk[16];
#pragma unroll
    for (int kp = 0; kp < 16; ++kp)
        wk[kp] = *(const uint2*)(WePk + kp * 256 + coff);

    const u32 pdu = *(const u32*)(P + (size_t)node * PST + 256 + coff);
    const float pb0 = bf2f_lo(pdu);
    const float pb1 = bf2f_hi(pdu);

    float acc0 = 0.f, acc1 = 0.f;
    const int s0r = row_start[node], s1r = row_start[node + 1];

    if (s1r > s0r) {
        const int jlast = s1r - 1;
        int j1 = (s0r + 1 < jlast) ? s0r + 1 : jlast;

        // scalar (wave-uniform) pipeline state
        int ja = __builtin_amdgcn_readfirstlane(s0r);
        int jb = __builtin_amdgcn_readfirstlane(j1);
        int sa = src_perm[ja];                 // uniform addr -> s_load
        int sb = src_perm[jb];
        u32 psa = *(const u32*)(P + (size_t)sa * PST + coff);
        u32 psb = *(const u32*)(P + (size_t)sb * PST + coff);
        const uint4* epa = (const uint4*)(eattr_p32 + (size_t)ja * 16);
        const uint4* epb = (const uint4*)(eattr_p32 + (size_t)jb * 16);
        uint4 ea0 = epa[0], ea1 = epa[1], ea2 = epa[2], ea3 = epa[3];
        uint4 eb0 = epb[0], eb1 = epb[1], eb2 = epb[2], eb3 = epb[3];

        for (int j = s0r; j < s1r; ++j) {
            int jc = (j + 2 < jlast) ? j + 2 : jlast;
            int jcs = __builtin_amdgcn_readfirstlane(jc);
            int sn = src_perm[jcs];            // s_load
            u32 psn = *(const u32*)(P + (size_t)sn * PST + coff);
            const uint4* epn = (const uint4*)(eattr_p32 + (size_t)jcs * 16);
            uint4 en0 = epn[0], en1 = epn[1], en2 = epn[2], en3 = epn[3];

            float q0 = pb0, q1 = pb1;
            q0 = fdot2u(ea0.x, wk[0].x, q0);  q1 = fdot2u(ea0.x, wk[0].y, q1);
            q0 = fdot2u(ea0.y, wk[1].x, q0);  q1 = fdot2u(ea0.y, wk[1].y, q1);
            q0 = fdot2u(ea0.z, wk[2].x, q0);  q1 = fdot2u(ea0.z, wk[2].y, q1);
            q0 = fdot2u(ea0.w, wk[3].x, q0);  q1 = fdot2u(ea0.w, wk[3].y, q1);
            q0 = fdot2u(ea1.x, wk[4].x, q0);  q1 = fdot2u(ea1.x, wk[4].y, q1);
            q0 = fdot2u(ea1.y, wk[5].x, q0);  q1 = fdot2u(ea1.y, wk[5].y, q1);
            q0 = fdot2u(ea1.z, wk[6].x, q0);  q1 = fdot2u(ea1.z, wk[6].y, q1);
            q0 = fdot2u(ea1.w, wk[7].x, q0);  q1 = fdot2u(ea1.w, wk[7].y, q1);
            q0 = fdot2u(ea2.x, wk[8].x, q0);  q1 = fdot2u(ea2.x, wk[8].y, q1);
            q0 = fdot2u(ea2.y, wk[9].x, q0);  q1 = fdot2u(ea2.y, wk[9].y, q1);
            q0 = fdot2u(ea2.z, wk[10].x, q0); q1 = fdot2u(ea2.z, wk[10].y, q1);
            q0 = fdot2u(ea2.w, wk[11].x, q0); q1 = fdot2u(ea2.w, wk[11].y, q1);
            q0 = fdot2u(ea3.x, wk[12].x, q0); q1 = fdot2u(ea3.x, wk[12].y, q1);
            q0 = fdot2u(ea3.y, wk[13].x, q0); q1 = fdot2u(ea3.y, wk[13].y, q1);
            q0 = fdot2u(ea3.z, wk[14].x, q0); q1 = fdot2u(ea3.z, wk[14].y, q1);
            q0 = fdot2u(ea3.w, wk[15].x, q0); q1 = fdot2u(ea3.w, wk[15].y, q1);

            q0 += bf2f_lo(psa);
            q1 += bf2f_hi(psa);
            acc0 += fmaxf(q0, 0.f);
            acc1 += fmaxf(q1, 0.f);

            psa = psb; psb = psn;
            ea0 = eb0; ea1 = eb1; ea2 = eb2; ea3 = eb3;
            eb0 = en0; eb1 = en1; eb2 = en2; eb3 = en3;
        }
    }

    const float idg = inv_deg[node];
    *(u32*)(aggZ + (size_t)node * 512 + coff) = packbf2(acc0 * idg, acc1 * idg);
}

// out[node] = dot(h4[node,:], h2w) + h2b  — one wave per node; h4 in Z[:,0:256]
__global__ __launch_bounds__(256) void head_out(
    const u16* __restrict__ h4Z,
    const float* __restrict__ h2w,
    const float* __restrict__ h2b,
    float* __restrict__ out)
{
    const int node = (int)((blockIdx.x * 256 + threadIdx.x) >> 6);
    const int lane = threadIdx.x & 63;
    if (node >= NN) return;
    const int col = lane * 4;
    u16x4 hv = *(const u16x4*)(h4Z + (size_t)node * 512 + col);
    float4 wv = *(const float4*)(h2w + col);
    float s = bf2f(hv[0]) * wv.x + bf2f(hv[1]) * wv.y +
              bf2f(hv[2]) * wv.z + bf2f(hv[3]) * wv.w;
    for (int off = 32; off > 0; off >>= 1)
        s += __shfl_down(s, off, 64);
    if (lane == 0) out[node] = s + h2b[0];
}

// ---------------- setup kernels ----------------
__global__ void zero_int(int* p, int n) {
    int i = blockIdx.x * 256 + threadIdx.x;
    if (i < n) p[i] = 0;
}

__global__ void hist_k(const int* __restrict__ ei, int* __restrict__ deg) {
    int e = blockIdx.x * 256 + threadIdx.x;
    if (e < NE) atomicAdd(&deg[ei[NE + e]], 1);
}

__global__ __launch_bounds__(256) void block_sum_k(const int* __restrict__ deg,
                                                   int* __restrict__ bsum) {
    __shared__ int sm[4];
    const int i = blockIdx.x * 256 + threadIdx.x;
    int v = (i < NN) ? deg[i] : 0;
    for (int off = 32; off > 0; off >>= 1)
        v += __shfl_down(v, off, 64);
    const int lane = threadIdx.x & 63;
    const int w = threadIdx.x >> 6;
    if (lane == 0) sm[w] = v;
    __syncthreads();
    if (threadIdx.x == 0)
        bsum[blockIdx.x] = sm[0] + sm[1] + sm[2] + sm[3];
}

__global__ __launch_bounds__(256) void scan_block_k(const int* __restrict__ bsum,
                                                    int* __restrict__ boff,
                                                    int* __restrict__ row_start) {
    __shared__ int sm[256];
    const int tid = threadIdx.x;
    int v = (tid < NBLK) ? bsum[tid] : 0;
    sm[tid] = v;
    __syncthreads();
    for (int o = 1; o < 256; o <<= 1) {
        int tv = (tid >= o) ? sm[tid - o] : 0;
        __syncthreads();
        sm[tid] += tv;
        __syncthreads();
    }
    if (tid < NBLK) boff[tid] = sm[tid] - v;  // exclusive
    if (tid == NBLK - 1) row_start[NN] = sm[tid];
}

__global__ __launch_bounds__(256) void writeback_k(const int* __restrict__ deg,
                                                   const int* __restrict__ boff,
                                                   int* __restrict__ row_start,
                                                   int* __restrict__ cursor,
                                                   float* __restrict__ inv_deg) {
    __shared__ int sm[256];
    const int tid = threadIdx.x;
    const int i = blockIdx.x * 256 + tid;
    int v = (i < NN) ? deg[i] : 0;
    sm[tid] = v;
    __syncthreads();
    for (int o = 1; o < 256; o <<= 1) {
        int tv = (tid >= o) ? sm[tid - o] : 0;
        __syncthreads();
        sm[tid] += tv;
        __syncthreads();
    }
    if (i < NN) {
        const int rs = boff[blockIdx.x] + sm[tid] - v;
        row_start[i] = rs;
        cursor[i]    = rs;
        inv_deg[i]   = 1.0f / fmaxf((float)v, 1.0f);
    }
}

__global__ void scatter_k(const int* __restrict__ ei, const float* __restrict__ eattr,
                          int* __restrict__ cursor, int* __restrict__ src_perm,
                          u32* __restrict__ eattr_p32) {
    int e = blockIdx.x * 256 + threadIdx.x;
    if (e >= NE) return;
    int s = ei[e], d = ei[NE + e];
    int pos = atomicAdd(&cursor[d], 1);
    src_perm[pos] = s;
    const float* sr = eattr + (size_t)e * 32;
    u32 pk[16];
#pragma unroll
    for (int j = 0; j < 16; ++j)
        pk[j] = packh2(sr[2 * j], sr[2 * j + 1]);
    uint4* dr = (uint4*)(eattr_p32 + (size_t)pos * 16);
    dr[0] = (uint4){pk[0], pk[1], pk[2], pk[3]};
    dr[1] = (uint4){pk[4], pk[5], pk[6], pk[7]};
    dr[2] = (uint4){pk[8], pk[9], pk[10], pk[11]};
    dr[3] = (uint4){pk[12], pk[13], pk[14], pk[15]};
}

// P-GEMM bias: [512] f32 per layer = [0(256) | eb(256)]
__global__ void bias_build(const float* __restrict__ e0b,
                           const float* __restrict__ eb1,
                           const float* __restrict__ eb2,
                           float* __restrict__ dst) {
    int i = blockIdx.x * 256 + threadIdx.x;
    if (i >= 1536) return;
    int l = i >> 9, c = i & 511;
    const float* s = (l == 0) ? e0b : (l == 1) ? eb1 : eb2;
    dst[i] = (c < 256) ? 0.f : s[c - 256];
}

// jobs: tr=1: dst[n*dstride+k] = bf16(src[k*256+n]), n in 0..255, k in 0..K-1
//       tr=2: We pack u32: dst32[kp*256+c] = packh2(src[2kp*256+c], src[(2kp+1)*256+c])
struct TJob { const float* src; u16* dst; int K; int ksh; int tr; int dstride; };
struct TJobs { TJob j[16]; };

__global__ void transpose_k(TJobs jobs) {
    TJob jb = jobs.j[blockIdx.y];
    int idx = blockIdx.x * 256 + threadIdx.x;
    if (idx >= (jb.K << 8)) return;
    if (jb.tr == 1) {
        int n = idx >> jb.ksh;
        int k = idx & (jb.K - 1);
        jb.dst[n * jb.dstride + k] = f2bf(jb.src[k * 256 + n]);
    } else {
        int kp = idx >> 8;
        int c = idx & 255;
        ((u32*)jb.dst)[idx] = packh2(jb.src[(2 * kp) * 256 + c],
                                     jb.src[(2 * kp + 1) * 256 + c]);
    }
}

// x (f32 [NN,128]) -> Z[:,256:384] bf16 (row stride 512)
__global__ void cvt_x(const float* __restrict__ src, u16* __restrict__ Z) {
    int i = blockIdx.x * 256 + threadIdx.x;
    if (i >= NN * 128) return;
    int n = i >> 7, c = i & 127;
    Z[(size_t)n * 512 + 256 + c] = f2bf(src[i]);
}

// ---------------------------------------------------------------------------
extern "C" void kernel_launch(void* const* d_in, const int* in_sizes, int n_in,
                              void* d_out, int out_size, void* d_ws, size_t ws_size,
                              hipStream_t stream) {
    const float* x     = (const float*)d_in[0];
    const int*   ei    = (const int*)d_in[1];
    const float* eattr = (const float*)d_in[2];
    const float* e0_w  = (const float*)d_in[3];
    const float* e0_b  = (const float*)d_in[4];
    const float* n0_w  = (const float*)d_in[5];
    const float* n0_b  = (const float*)d_in[6];
    const float* e_w   = (const float*)d_in[7];
    const float* e_b   = (const float*)d_in[8];
    const float* n_w   = (const float*)d_in[9];
    const float* n_b   = (const float*)d_in[10];
    const float* h1_w  = (const float*)d_in[11];
    const float* h1_b  = (const float*)d_in[12];
    const float* h2_w  = (const float*)d_in[13];
    const float* h2_b  = (const float*)d_in[14];
    float* out = (float*)d_out;
    (void)in_sizes; (void)n_in; (void)out_size; (void)ws_size;

    char* base = (char*)d_ws;
    size_t off = 0;
    auto alloc = [&](size_t nbytes) -> void* {
        void* p = base + off;
        off += (nbytes + 255) & ~(size_t)255;
        return p;
    };

    int*   deg       = (int*)alloc(NN * 4);
    int*   row_start = (int*)alloc((NN + 1) * 4);
    int*   cursor    = (int*)alloc(NN * 4);
    float* invdeg    = (float*)alloc(NN * 4);
    int*   bsum      = (int*)alloc(NBLK * 4);
    int*   boff      = (int*)alloc(NBLK * 4);
    int*   src_perm  = (int*)alloc(NE * 4);
    u32*   eattr_p32 = (u32*)alloc((size_t)NE * 16 * 4);
    u16*   WcatT0    = (u16*)alloc(512 * 128 * 2);
    u16*   WcatT1    = (u16*)alloc(512 * 256 * 2);
    u16*   WcatT2    = (u16*)alloc(512 * 256 * 2);
    u32*   WePk0     = (u32*)alloc(16 * 256 * 4);
    u32*   WePk1     = (u32*)alloc(16 * 256 * 4);
    u32*   WePk2     = (u32*)alloc(16 * 256 * 4);
    u16*   BcatT0    = (u16*)alloc(256 * 384 * 2);
    u16*   BcatT1    = (u16*)alloc(256 * 512 * 2);
    u16*   BcatT2    = (u16*)alloc(256 * 512 * 2);
    u16*   H1T       = (u16*)alloc(256 * 256 * 2);
    float* bias512   = (float*)alloc(3 * 512 * 4);
    u16*   P         = (u16*)alloc((size_t)NN * PST * 2);
    u16*   Z0        = (u16*)alloc((size_t)NN * 512 * 2);
    u16*   Z1        = (u16*)alloc((size_t)NN * 512 * 2);

    // ---- CSR build + weight prep ----
    zero_int<<<(NN + 255) / 256, 256, 0, stream>>>(deg, NN);
    hist_k<<<(NE + 255) / 256, 256, 0, stream>>>(ei, deg);
    block_sum_k<<<NBLK, 256, 0, stream>>>(deg, bsum);
    scan_block_k<<<1, 256, 0, stream>>>(bsum, boff, row_start);
    writeback_k<<<NBLK, 256, 0, stream>>>(deg, boff, row_start, cursor, invdeg);
    scatter_k<<<(NE + 255) / 256, 256, 0, stream>>>(ei, eattr, cursor, src_perm, eattr_p32);
    bias_build<<<6, 256, 0, stream>>>(e0_b, e_b, e_b + 256, bias512);

    const float* ew2 = e_w + 544 * 256;
    const float* nw2 = n_w + 512 * 256;

    TJobs tj;
    auto setj = [&](int i, const float* s, void* d, int K, int tr, int dstride) {
        tj.j[i].src = s; tj.j[i].dst = (u16*)d; tj.j[i].K = K; tj.j[i].tr = tr;
        tj.j[i].dstride = dstride;
        tj.j[i].ksh = (K == 256) ? 8 : (K == 128 ? 7 : 5);
    };
    // P-GEMM weights: WcatT[n(512)][K] = [Ws rows | Wd rows] transposed
    setj(0,  e0_w,             WcatT0,             128, 1, 128);
    setj(1,  e0_w + 128 * 256, WcatT0 + 256 * 128, 128, 1, 128);
    setj(2,  e_w,              WcatT1,             256, 1, 256);
    setj(3,  e_w + 256 * 256,  WcatT1 + 256 * 256, 256, 1, 256);
    setj(4,  ew2,              WcatT2,             256, 1, 256);
    setj(5,  ew2 + 256 * 256,  WcatT2 + 256 * 256, 256, 1, 256);
    // node-GEMM weights: BcatT[n(256)][k] = [nbot(k<256) | ntop]
    setj(6,  n0_w + 128 * 256, BcatT0,             256, 1, 384);
    setj(7,  n0_w,             BcatT0 + 256,       128, 1, 384);
    setj(8,  n_w + 256 * 256,  BcatT1,             256, 1, 512);
    setj(9,  n_w,              BcatT1 + 256,       256, 1, 512);
    setj(10, nw2 + 256 * 256,  BcatT2,             256, 1, 512);
    setj(11, nw2,              BcatT2 + 256,       256, 1, 512);
    setj(12, h1_w,             H1T,                256, 1, 256);
    // edge-attr weights, packed f16 pairs
    setj(13, e0_w + 256 * 256, WePk0,              16,  2, 0);
    setj(14, e_w + 512 * 256,  WePk1,              16,  2, 0);
    setj(15, ew2 + 512 * 256,  WePk2,              16,  2, 0);
    transpose_k<<<dim3(256, 16), 256, 0, stream>>>(tj);

    cvt_x<<<(NN * 128 + 255) / 256, 256, 0, stream>>>(x, Z0);

    const int MT = (NN + 127) / 128;  // 391
    const int AGG_BLK = (2 * NN) / 4;  // 2 waves/node, 4 waves/block = 25000
    u16* WcatT[3] = {WcatT0, WcatT1, WcatT2};
    u32* WePk[3]  = {WePk0, WePk1, WePk2};
    u16* BcatT[3] = {BcatT0, BcatT1, BcatT2};
    const float* nbs[3] = {n0_b, n_b, n_b + 256};
    u16* Zin[3]  = {Z0, Z1, Z0};
    u16* Zout[3] = {Z1, Z0, Z1};
    const int kin[3]   = {128, 256, 256};
    const int knode[3] = {384, 512, 512};

    for (int l = 0; l < 3; ++l) {
        // P = h @ [Ws | Wd] + [0|eb]  -> [NN, 512] (stride PST)
        gemm_bt<<<dim3(MT, 4), 256, 0, stream>>>(Zin[l] + 256, 512, WcatT[l], P, PST,
                                                 NN, kin[l], bias512 + l * 512, 0);
        // agg = mean_dst relu(Ps[src] + Pd[dst] + eattr@We)
        edge_agg_fused<<<AGG_BLK, 256, 0, stream>>>(P, eattr_p32, WePk[l], row_start,
                                                    src_perm, invdeg, Zin[l]);
        // h' = relu([agg | h] @ [nbot; ntop] + nb)
        gemm_bt<<<dim3(MT, 2), 256, 0, stream>>>(Zin[l], 512, BcatT[l], Zout[l] + 256, 512,
                                                 NN, knode[l], nbs[l], 1);
    }
    // head: h4 = relu(h3 @ h1_w + h1_b) -> Z1[:,0:256]; out = h4 @ h2_w + h2_b
    gemm_bt<<<dim3(MT, 2), 256, 0, stream>>>(Z1 + 256, 512, H1T, Z1, 512,
                                             NN, 256, h1_b, 1);
    head_out<<<NN / 4, 256, 0, stream>>>(Z1, h2_w, h2_b, out);
}